// Round 7
// baseline (3385.803 us; speedup 1.0000x reference)
//
#include <hip/hip_runtime.h>
#include <hip/hip_bf16.h>
#include <cstdint>

#define NN 131072      // nodes
#define NE 524288      // directed edges
#define DIM 275        // feature dim
#define DP 288         // padded stride (multiple of 16)
#define NFEAT 9
#define NVOC 128
#define NLAY 5
#define NPG 64
#define NGRAPH 2048
#define BN_EPS 1e-5f
#define BM 128
#define BK 32
#define NEPAD (NE + 3 * NN)   // max padded edge count
#define LDSE 1280             // per-block staged edge indices (32 nodes)

typedef unsigned short u16;
typedef __attribute__((ext_vector_type(8))) short s16x8;
typedef __attribute__((ext_vector_type(4))) float f32x4;

__device__ __forceinline__ float bf2f(u16 u) {
  union { unsigned int i; float f; } x; x.i = ((unsigned int)u) << 16; return x.f;
}
__device__ __forceinline__ u16 f2bf(float f) {
  union { float f; unsigned int i; } x; x.f = f;
  unsigned int r = x.i + 0x7fffu + ((x.i >> 16) & 1u);
  return (u16)(r >> 16);
}
__device__ __forceinline__ void acc4(float* a, uint2 m) {
  a[0] += bf2f((u16)m.x); a[1] += bf2f((u16)(m.x >> 16));
  a[2] += bf2f((u16)m.y); a[3] += bf2f((u16)(m.y >> 16));
}

// ---------------- graph preprocessing ----------------

__global__ void hist_kernel(const int* __restrict__ ei, int* __restrict__ cnt) {
  int e = blockIdx.x * 256 + threadIdx.x;
  if (e < NE) atomicAdd(&cnt[ei[NE + e]], 1);
}

__global__ void pad_dinv_kernel(const int* __restrict__ cnt, int* __restrict__ cnt_pad,
                                float* __restrict__ dinv) {
  int v = blockIdx.x * 256 + threadIdx.x;
  if (v < NN) {
    int c = cnt[v];
    cnt_pad[v] = (c + 3) & ~3;
    dinv[v] = rsqrtf(1.0f + (float)c);
  }
}

// counting sort of nodes by padded degree (perf heuristic only)
__global__ void bucket_hist_kernel(const int* __restrict__ cnt_pad, int* __restrict__ bcnt) {
  int v = blockIdx.x * 256 + threadIdx.x;
  if (v < NN) {
    int b = cnt_pad[v] >> 2; if (b > 255) b = 255;
    atomicAdd(&bcnt[b], 1);
  }
}

__global__ void bucket_scan_kernel(int* __restrict__ bcnt, int* __restrict__ bcur) {
  __shared__ int buf[2][256];
  int t = threadIdx.x;
  int v = bcnt[t];
  buf[0][t] = v;
  __syncthreads();
  int cur = 0;
  for (int off = 1; off < 256; off <<= 1) {
    int x = buf[cur][t];
    if (t >= off) x += buf[cur][t - off];
    buf[cur ^ 1][t] = x;
    __syncthreads();
    cur ^= 1;
  }
  int ex = buf[cur][t] - v;
  bcnt[t] = ex;
  bcur[t] = ex;
}

__global__ void perm_fill_kernel(const int* __restrict__ cnt_pad, int* __restrict__ bcur,
                                 int* __restrict__ perm, int* __restrict__ cs) {
  int v = blockIdx.x * 256 + threadIdx.x;
  if (v < NN) {
    int c = cnt_pad[v];
    int b = c >> 2; if (b > 255) b = 255;
    int pos = atomicAdd(&bcur[b], 1);
    perm[pos] = v;
    cs[pos] = c;
  }
}

__global__ void scan_block_kernel(const int* __restrict__ in, int* __restrict__ out_ex,
                                  int* __restrict__ partials) {
  __shared__ int buf[2][1024];
  int t = threadIdx.x;
  int idx = blockIdx.x * 1024 + t;
  int v = in[idx];
  buf[0][t] = v;
  __syncthreads();
  int cur = 0;
  for (int off = 1; off < 1024; off <<= 1) {
    int x = buf[cur][t];
    if (t >= off) x += buf[cur][t - off];
    buf[cur ^ 1][t] = x;
    __syncthreads();
    cur ^= 1;
  }
  out_ex[idx] = buf[cur][t] - v;
  if (t == 1023) partials[blockIdx.x] = buf[cur][t];
}

__global__ void scan_partials_kernel(int* partials) {
  __shared__ int buf[2][128];
  int t = threadIdx.x;
  int v = partials[t];
  buf[0][t] = v;
  __syncthreads();
  int cur = 0;
  for (int off = 1; off < 128; off <<= 1) {
    int x = buf[cur][t];
    if (t >= off) x += buf[cur][t - off];
    buf[cur ^ 1][t] = x;
    __syncthreads();
    cur ^= 1;
  }
  partials[t] = buf[cur][t] - v;
}

// indptr is in SORTED order; cursor is indexed by ORIGINAL node id.
__global__ void add_offsets_kernel(int* __restrict__ indptr, const int* __restrict__ partials,
                                   int* __restrict__ cursor, const int* __restrict__ cs,
                                   const int* __restrict__ perm) {
  int i = blockIdx.x * 256 + threadIdx.x;
  if (i < NN) {
    int v = indptr[i] + partials[i >> 10];
    indptr[i] = v;
    cursor[perm[i]] = v;
    if (i == NN - 1) indptr[NN] = v + cs[NN - 1];
  }
}

__global__ void fill_csr_kernel(const int* __restrict__ ei, int* __restrict__ cursor,
                                int* __restrict__ srcs) {
  int e = blockIdx.x * 256 + threadIdx.x;
  if (e < NE) {
    int c = ei[NE + e];
    int p = atomicAdd(&cursor[c], 1);
    srcs[p] = ei[e];
  }
}

// pad slots point at the all-zeros row NN
__global__ void pad_fill_kernel(const int* __restrict__ cursor, const int* __restrict__ indptr,
                                const int* __restrict__ perm, int* __restrict__ srcs) {
  int i = blockIdx.x * 256 + threadIdx.x;
  if (i < NN) {
    int v = perm[i];
    int pe = indptr[i + 1];
    for (int p = cursor[v]; p < pe; ++p) srcs[p] = NN;
  }
}

__global__ void zrow_kernel(u16* __restrict__ P, u16* __restrict__ Q) {
  int i = threadIdx.x;
  if (i < DP) {
    P[(size_t)NN * DP + i] = 0;
    Q[(size_t)NN * DP + i] = 0;
  }
}

__global__ void wpad_kernel(const float* __restrict__ convW, const float* __restrict__ postW,
                            u16* __restrict__ Wp) {
  int i = blockIdx.x * 256 + threadIdx.x;
  const int total = 6 * 320 * DP;
  if (i >= total) return;
  int k = i % DP;
  int r = i / DP;
  int j = r % 320;
  int m = r / 320;
  float val = 0.f;
  if (j < DIM && k < DIM)
    val = (m < 5) ? convW[((size_t)m * DIM + j) * DIM + k] : postW[(size_t)j * DIM + k];
  Wp[i] = f2bf(val);
}

// ---------------- atom encoder ----------------

__global__ void embed_kernel(const int* __restrict__ xa, const float* __restrict__ emb,
                             u16* __restrict__ P) {
  int n = blockIdx.x;
  int idx[NFEAT];
#pragma unroll
  for (int f = 0; f < NFEAT; ++f) idx[f] = xa[n * NFEAT + f];
  for (int d = threadIdx.x; d < DP; d += 128) {
    float s = 0.f;
    if (d < DIM) {
#pragma unroll
      for (int f = 0; f < NFEAT; ++f) s += emb[((size_t)f * NVOC + idx[f]) * DIM + d];
    }
    P[(size_t)n * DP + d] = f2bf(s);
  }
}

// ---------------- MFMA GEMM (BM=128, col tile 160, 2 col passes) ----------------

__device__ __forceinline__ uint4 xform8(uint4 r, const float* __restrict__ sc,
                                        const float* __restrict__ sh, int k) {
  union { uint4 u; u16 h[8]; } in, out;
  in.u = r;
#pragma unroll
  for (int j = 0; j < 8; ++j) {
    float x = fmaf(bf2f(in.h[j]), sc[k + j], sh[k + j]);
    out.h[j] = f2bf(fmaxf(x, 0.f));
  }
  return out.u;
}

__launch_bounds__(256)
__global__ void gemm_kernel(const u16* __restrict__ A, const u16* __restrict__ Wp,
                            u16* __restrict__ C,
                            const float* __restrict__ scale, const float* __restrict__ shift,
                            const float* __restrict__ rowscale, const float* __restrict__ colbias) {
  __shared__ __align__(16) u16 Asl[BM * BK];     // 8 KB
  __shared__ __align__(16) u16 Bsl[160 * BK];    // 10 KB
  const int tid = threadIdx.x;
  const int lane = tid & 63;
  const int wv = tid >> 6, wm = wv & 1, wn = wv >> 1;   // waves 2(M) x 2(N)
  const int b = blockIdx.x;
  const int grp = b >> 4, rem = b & 15;
  const int col = rem >> 3, pan8 = rem & 7;
  const int row0 = (grp * 8 + pan8) * BM, col0 = col * 128;

  const int sr = tid >> 2, ssl = tid & 3;
  const int swz = ((ssl ^ (sr & 3) ^ ((sr >> 2) & 3)) << 3);
  const int aw0 = sr * BK + swz;
  const u16* ag0 = A + (size_t)(row0 + sr) * DP + ssl * 8;
  const u16* ag1 = ag0 + (size_t)64 * DP;
  const u16* bg0 = Wp + (size_t)(col0 + sr) * DP + ssl * 8;
  const u16* bg1 = bg0 + (size_t)64 * DP;
  const u16* bg2 = bg0 + (size_t)128 * DP;
  const bool st2 = (tid < 128);

  const int fr = lane & 15, fs = lane >> 4;
  const int fswz = ((fs ^ (fr & 3) ^ ((fr >> 2) & 3)) << 3);
  int aoff[4], boff[5];
#pragma unroll
  for (int i = 0; i < 4; ++i) aoff[i] = (wm * 64 + i * 16 + fr) * BK + fswz;
#pragma unroll
  for (int j = 0; j < 5; ++j) boff[j] = (wn * 80 + j * 16 + fr) * BK + fswz;

  const bool bn = (scale != nullptr);
  const int NS = DP / BK;

  {
    uint4 ra0 = *(const uint4*)(ag0);
    uint4 ra1 = *(const uint4*)(ag1);
    uint4 rb0 = *(const uint4*)(bg0);
    uint4 rb1 = *(const uint4*)(bg1);
    uint4 rb2;
    if (st2) rb2 = *(const uint4*)(bg2);
    if (bn) {
      ra0 = xform8(ra0, scale, shift, ssl * 8);
      ra1 = xform8(ra1, scale, shift, ssl * 8);
    }
    *(uint4*)&Asl[aw0] = ra0;
    *(uint4*)&Asl[aw0 + 64 * BK] = ra1;
    *(uint4*)&Bsl[aw0] = rb0;
    *(uint4*)&Bsl[aw0 + 64 * BK] = rb1;
    if (st2) *(uint4*)&Bsl[aw0 + 128 * BK] = rb2;
  }
  __syncthreads();

  f32x4 acc[4][5];
#pragma unroll
  for (int i = 0; i < 4; ++i)
#pragma unroll
    for (int j = 0; j < 5; ++j) acc[i][j] = (f32x4){0.f, 0.f, 0.f, 0.f};

  for (int s = 0; s < NS; ++s) {
    const bool more = (s < NS - 1);
    uint4 na0, na1, nb0, nb1, nb2;
    if (more) {
      na0 = *(const uint4*)(ag0 + (s + 1) * BK);
      na1 = *(const uint4*)(ag1 + (s + 1) * BK);
      nb0 = *(const uint4*)(bg0 + (s + 1) * BK);
      nb1 = *(const uint4*)(bg1 + (s + 1) * BK);
      if (st2) nb2 = *(const uint4*)(bg2 + (s + 1) * BK);
    }
    s16x8 af[4], bf[5];
#pragma unroll
    for (int i = 0; i < 4; ++i) af[i] = *(const s16x8*)&Asl[aoff[i]];
#pragma unroll
    for (int j = 0; j < 5; ++j) bf[j] = *(const s16x8*)&Bsl[boff[j]];
#pragma unroll
    for (int i = 0; i < 4; ++i)
#pragma unroll
      for (int j = 0; j < 5; ++j)
        acc[i][j] = __builtin_amdgcn_mfma_f32_16x16x32_bf16(af[i], bf[j], acc[i][j], 0, 0, 0);
    if (more) {
      __syncthreads();
      int k2 = (s + 1) * BK + ssl * 8;
      if (bn) {
        na0 = xform8(na0, scale, shift, k2);
        na1 = xform8(na1, scale, shift, k2);
      }
      *(uint4*)&Asl[aw0] = na0;
      *(uint4*)&Asl[aw0 + 64 * BK] = na1;
      *(uint4*)&Bsl[aw0] = nb0;
      *(uint4*)&Bsl[aw0 + 64 * BK] = nb1;
      if (st2) *(uint4*)&Bsl[aw0 + 128 * BK] = nb2;
      __syncthreads();
    }
  }

#pragma unroll
  for (int i = 0; i < 4; ++i) {
    int gr0 = row0 + wm * 64 + i * 16 + fs * 4;
    float rs[4];
#pragma unroll
    for (int r = 0; r < 4; ++r) rs[r] = rowscale ? rowscale[gr0 + r] : 1.f;
#pragma unroll
    for (int j = 0; j < 5; ++j) {
      int gc = col0 + wn * 80 + j * 16 + fr;
      if (gc < DP) {
        float cb = (colbias && gc < DIM) ? colbias[gc] : 0.f;
#pragma unroll
        for (int r = 0; r < 4; ++r) {
          u16 o = (gc < DIM) ? f2bf(fmaf(acc[i][j][r], rs[r], cb)) : (u16)0;
          C[(size_t)(gr0 + r) * DP + gc] = o;
        }
      }
    }
  }
}

// ---------------- SpMM v4: degree-sorted quad-interleave ----------------
// Nodes processed in degree-sorted order (perm). Each wave handles 8 sorted
// nodes as 2 quads of 4 equal-degree nodes -> 16 independent c0 gathers in
// flight, near-zero predication waste. Block = 32 nodes (4096 blocks).

__launch_bounds__(256)
__global__ void spmm_kernel(const u16* __restrict__ X, u16* __restrict__ Y,
                            const int* __restrict__ indptr, const int* __restrict__ srcs,
                            const int* __restrict__ perm,
                            const float* __restrict__ dinv, const float* __restrict__ bias,
                            float* __restrict__ bn_sum, float* __restrict__ bn_sq) {
  __shared__ float ls[DP], lq[DP];
  __shared__ int sptr[33], sperm[32];
  __shared__ int sidx[LDSE];
  int tid = threadIdx.x;
  for (int i = tid; i < DP; i += 256) { ls[i] = 0.f; lq[i] = 0.f; }
  int vb = blockIdx.x * 32;   // sorted-index base
  if (tid < 33) sptr[tid] = indptr[vb + tid];
  if (tid >= 64 && tid < 96) sperm[tid - 64] = perm[vb + tid - 64];
  __syncthreads();
  int ebase = sptr[0];
  int ecnt = sptr[32] - ebase;
  const int* ip;
  if (ecnt <= LDSE) {
    for (int i = tid; i < ecnt; i += 256) sidx[i] = srcs[ebase + i];
    ip = sidx;
  } else {
    ip = srcs + ebase;
  }
  __syncthreads();

  int lane = tid & 63, wv = tid >> 6;
  int c0 = lane << 2;
  int c1 = 256 + (lane << 2);
  bool tl = lane < 8;
  float bia[4], bib[4];
#pragma unroll
  for (int j = 0; j < 4; ++j) bia[j] = bias[c0 + j];
#pragma unroll
  for (int j = 0; j < 4; ++j) bib[j] = (tl && c1 + j < DIM) ? bias[c1 + j] : 0.f;
  float s0[4] = {}, q0[4] = {}, s1[4] = {}, q1[4] = {};

  for (int g = 0; g < 2; ++g) {
    int nb = wv * 8 + g * 4;   // local sorted index of quad start
    int vid[4], eb[4], ne[4];
#pragma unroll
    for (int j = 0; j < 4; ++j) {
      vid[j] = sperm[nb + j];
      eb[j] = sptr[nb + j] - ebase;
      ne[j] = sptr[nb + j + 1] - sptr[nb + j];
    }
    int nemax = max(max(ne[0], ne[1]), max(ne[2], ne[3]));
    const u16* xs[4];
#pragma unroll
    for (int j = 0; j < 4; ++j) xs[j] = X + (size_t)vid[j] * DP;
    float A0[4][4] = {}, A1[4][4] = {};
    {
      uint2 ms[4];
#pragma unroll
      for (int j = 0; j < 4; ++j) ms[j] = *(const uint2*)(xs[j] + c0);
#pragma unroll
      for (int j = 0; j < 4; ++j) acc4(A0[j], ms[j]);
      if (tl) {
        uint2 ts[4];
#pragma unroll
        for (int j = 0; j < 4; ++j) ts[j] = *(const uint2*)(xs[j] + c1);
#pragma unroll
        for (int j = 0; j < 4; ++j) acc4(A1[j], ts[j]);
      }
    }
    for (int e = 0; e < nemax; e += 4) {
      const u16* p[4][4];
#pragma unroll
      for (int j = 0; j < 4; ++j) {
        bool av = e < ne[j];
        int o = av ? eb[j] + e : 0;
#pragma unroll
        for (int k = 0; k < 4; ++k) {
          int t = ip[o + k];
          p[j][k] = X + (size_t)(av ? t : NN) * DP;
        }
      }
      uint2 m[4][4];
#pragma unroll
      for (int j = 0; j < 4; ++j)
#pragma unroll
        for (int k = 0; k < 4; ++k) m[j][k] = *(const uint2*)(p[j][k] + c0);
#pragma unroll
      for (int j = 0; j < 4; ++j)
#pragma unroll
        for (int k = 0; k < 4; ++k) acc4(A0[j], m[j][k]);
      if (tl) {
        uint2 t[4][4];
#pragma unroll
        for (int j = 0; j < 4; ++j)
#pragma unroll
          for (int k = 0; k < 4; ++k) t[j][k] = *(const uint2*)(p[j][k] + c1);
#pragma unroll
        for (int j = 0; j < 4; ++j)
#pragma unroll
          for (int k = 0; k < 4; ++k) acc4(A1[j], t[j][k]);
      }
    }
#pragma unroll
    for (int j = 0; j < 4; ++j) {
      float dv = dinv[vid[j]];
      u16* yv = Y + (size_t)vid[j] * DP;
      float y[4];
#pragma unroll
      for (int q = 0; q < 4; ++q) {
        y[q] = fmaf(dv, A0[j][q], bia[q]);
        s0[q] += y[q]; q0[q] += y[q] * y[q];
      }
      uint2 wo;
      wo.x = (unsigned)f2bf(y[0]) | ((unsigned)f2bf(y[1]) << 16);
      wo.y = (unsigned)f2bf(y[2]) | ((unsigned)f2bf(y[3]) << 16);
      *(uint2*)(yv + c0) = wo;
      if (tl) {
        float z[4];
#pragma unroll
        for (int q = 0; q < 4; ++q) {
          z[q] = fmaf(dv, A1[j][q], bib[q]);
          s1[q] += z[q]; q1[q] += z[q] * z[q];
        }
        uint2 w2;
        w2.x = (unsigned)f2bf(z[0]) | ((unsigned)f2bf(z[1]) << 16);
        w2.y = (unsigned)f2bf(z[2]) | ((unsigned)f2bf(z[3]) << 16);
        *(uint2*)(yv + c1) = w2;
      }
    }
  }

#pragma unroll
  for (int j = 0; j < 4; ++j) { atomicAdd(&ls[c0 + j], s0[j]); atomicAdd(&lq[c0 + j], q0[j]); }
  if (tl) {
#pragma unroll
    for (int j = 0; j < 4; ++j) { atomicAdd(&ls[c1 + j], s1[j]); atomicAdd(&lq[c1 + j], q1[j]); }
  }
  __syncthreads();
  for (int i = tid; i < DP; i += 256) {
    atomicAdd(&bn_sum[i], ls[i]);
    atomicAdd(&bn_sq[i], lq[i]);
  }
}

__global__ void bn_finalize_kernel(const float* __restrict__ bn_sum, const float* __restrict__ bn_sq,
                                   const float* __restrict__ gamma, const float* __restrict__ beta,
                                   float* __restrict__ scale, float* __restrict__ shift) {
  int d = threadIdx.x;
  if (d >= DP) return;
  if (d < DIM) {
    const float invN = 1.0f / (float)NN;
    float mu = bn_sum[d] * invN;
    float var = bn_sq[d] * invN - mu * mu;
    float rstd = rsqrtf(var + BN_EPS);
    float sc = gamma[d] * rstd;
    scale[d] = sc;
    shift[d] = fmaf(-mu, sc, beta[d]);
  } else {
    scale[d] = 0.f;
    shift[d] = 0.f;
  }
}

// ---------------- MFMA Gram decode ----------------

__launch_bounds__(256)
__global__ void decode_kernel(const u16* __restrict__ H, float* __restrict__ out) {
  __shared__ __align__(16) u16 tile[4][2][NPG * BK];
  int tid = threadIdx.x, lane = tid & 63, wv = tid >> 6;
  int g = blockIdx.x * 4 + wv;
  const u16* Hg = H + (size_t)g * NPG * DP;
  const int ssl = lane & 3;
  int soff[4];
  const u16* sg[4];
#pragma unroll
  for (int i = 0; i < 4; ++i) {
    int r = (lane >> 2) + i * 16;
    soff[i] = r * BK + ((ssl ^ (r & 3) ^ ((r >> 2) & 3)) << 3);
    sg[i] = Hg + (size_t)r * DP + ssl * 8;
  }
  const int fr = lane & 15, fs = lane >> 4;
  const int fswz = ((fs ^ (fr & 3) ^ ((fr >> 2) & 3)) << 3);
  int foff[4];
#pragma unroll
  for (int i = 0; i < 4; ++i) foff[i] = (i * 16 + fr) * BK + fswz;

  u16* t0 = tile[wv][0];
  u16* t1 = tile[wv][1];
  uint4 rg[4];
#pragma unroll
  for (int i = 0; i < 4; ++i) rg[i] = *(const uint4*)(sg[i]);
#pragma unroll
  for (int i = 0; i < 4; ++i) *(uint4*)&t0[soff[i]] = rg[i];

  f32x4 acc[4][4];
#pragma unroll
  for (int i = 0; i < 4; ++i)
#pragma unroll
    for (int j = 0; j < 4; ++j) acc[i][j] = (f32x4){0.f, 0.f, 0.f, 0.f};

  for (int s = 0; s < DP / BK; ++s) {
    u16* cur = (s & 1) ? t1 : t0;
    u16* nxt = (s & 1) ? t0 : t1;
    const bool more = (s < DP / BK - 1);
    if (more) {
#pragma unroll
      for (int i = 0; i < 4; ++i) rg[i] = *(const uint4*)(sg[i] + (s + 1) * BK);
    }
    s16x8 af[4];
#pragma unroll
    for (int i = 0; i < 4; ++i) af[i] = *(const s16x8*)&cur[foff[i]];
#pragma unroll
    for (int i = 0; i < 4; ++i)
#pragma unroll
      for (int j = 0; j < 4; ++j)
        acc[i][j] = __builtin_amdgcn_mfma_f32_16x16x32_bf16(af[i], af[j], acc[i][j], 0, 0, 0);
    if (more) {
#pragma unroll
      for (int i = 0; i < 4; ++i) *(uint4*)&nxt[soff[i]] = rg[i];
    }
  }
  float* og = out + (size_t)g * NPG * NPG;
#pragma unroll
  for (int i = 0; i < 4; ++i) {
    int m0 = i * 16 + fs * 4;
#pragma unroll
    for (int j = 0; j < 4; ++j) {
      int n = j * 16 + fr;
#pragma unroll
      for (int r = 0; r < 4; ++r) og[(m0 + r) * NPG + n] = acc[i][j][r];
    }
  }
}

// ---------------- launch ----------------

extern "C" void kernel_launch(void* const* d_in, const int* in_sizes, int n_in,
                              void* d_out, int out_size, void* d_ws, size_t ws_size,
                              hipStream_t stream) {
  const int* xa = (const int*)d_in[0];
  const int* ei = (const int*)d_in[1];
  const float* emb = (const float*)d_in[2];
  const float* convW = (const float*)d_in[3];
  const float* convB = (const float*)d_in[4];
  const float* gamma = (const float*)d_in[5];
  const float* beta = (const float*)d_in[6];
  const float* postW = (const float*)d_in[7];
  const float* postB = (const float*)d_in[8];
  float* out = (float*)d_out;

  char* w = (char*)d_ws;
  u16* P = (u16*)w;          w += (size_t)(NN + 1) * DP * sizeof(u16);
  u16* Q = (u16*)w;          w += (size_t)(NN + 1) * DP * sizeof(u16);
  u16* Wp = (u16*)w;         w += (size_t)6 * 320 * DP * sizeof(u16);
  float* dinv = (float*)w;   w += (size_t)NN * sizeof(float);
  int* cnt = (int*)w;        w += (size_t)NN * sizeof(int);
  int* bcnt = (int*)w;       w += 256 * sizeof(int);
  int* bcur = (int*)w;       w += 256 * sizeof(int);
  int* cnt_pad = (int*)w;    w += (size_t)NN * sizeof(int);
  int* perm = (int*)w;       w += (size_t)NN * sizeof(int);
  int* cs = (int*)w;         w += (size_t)NN * sizeof(int);
  int* indptr = (int*)w;     w += (size_t)(NN + 64) * sizeof(int);
  int* cursor = (int*)w;     w += (size_t)NN * sizeof(int);
  int* srcs = (int*)w;       w += (size_t)NEPAD * sizeof(int);
  int* partials = (int*)w;   w += 256 * sizeof(int);
  float* bn_sum = (float*)w; w += DP * sizeof(float);
  float* bn_sq = (float*)w;  w += DP * sizeof(float);
  float* bnscale = (float*)w; w += DP * sizeof(float);
  float* bnshift = (float*)w; w += DP * sizeof(float);

  size_t need = (size_t)(w - (char*)d_ws);
  if (ws_size < need) return;

  // zero cnt + bcnt + bcur in one memset (adjacent in layout)
  hipMemsetAsync(cnt, 0, ((size_t)NN + 512) * sizeof(int), stream);
  hist_kernel<<<NE / 256, 256, 0, stream>>>(ei, cnt);
  pad_dinv_kernel<<<NN / 256, 256, 0, stream>>>(cnt, cnt_pad, dinv);
  bucket_hist_kernel<<<NN / 256, 256, 0, stream>>>(cnt_pad, bcnt);
  bucket_scan_kernel<<<1, 256, 0, stream>>>(bcnt, bcur);
  perm_fill_kernel<<<NN / 256, 256, 0, stream>>>(cnt_pad, bcur, perm, cs);
  scan_block_kernel<<<NN / 1024, 1024, 0, stream>>>(cs, indptr, partials);
  scan_partials_kernel<<<1, 128, 0, stream>>>(partials);
  add_offsets_kernel<<<NN / 256, 256, 0, stream>>>(indptr, partials, cursor, cs, perm);
  fill_csr_kernel<<<NE / 256, 256, 0, stream>>>(ei, cursor, srcs);
  pad_fill_kernel<<<NN / 256, 256, 0, stream>>>(cursor, indptr, perm, srcs);
  wpad_kernel<<<(6 * 320 * DP + 255) / 256, 256, 0, stream>>>(convW, postW, Wp);
  embed_kernel<<<NN, 128, 0, stream>>>(xa, emb, P);
  zrow_kernel<<<1, 288, 0, stream>>>(P, Q);

  for (int l = 0; l < NLAY; ++l) {
    gemm_kernel<<<(NN / BM) * 2, 256, 0, stream>>>(
        P, Wp + (size_t)l * 320 * DP, Q,
        l ? bnscale : nullptr, l ? bnshift : nullptr, dinv, nullptr);
    hipMemsetAsync(bn_sum, 0, 2 * DP * sizeof(float), stream);
    spmm_kernel<<<NN / 32, 256, 0, stream>>>(Q, P, indptr, srcs, perm, dinv,
                                             convB + (size_t)l * DIM, bn_sum, bn_sq);
    bn_finalize_kernel<<<1, DP, 0, stream>>>(bn_sum, bn_sq, gamma + (size_t)l * DIM,
                                             beta + (size_t)l * DIM, bnscale, bnshift);
  }

  gemm_kernel<<<(NN / BM) * 2, 256, 0, stream>>>(
      P, Wp + (size_t)5 * 320 * DP, Q, bnscale, bnshift, nullptr, postB);

  decode_kernel<<<NGRAPH / 4, 256, 0, stream>>>(Q, out);
}

// Round 8
// 1282.126 us; speedup vs baseline: 2.6408x; 2.6408x over previous
//
#include <hip/hip_runtime.h>
#include <hip/hip_bf16.h>
#include <cstdint>

#define NN 131072      // nodes
#define NE 524288      // directed edges
#define DIM 275        // feature dim
#define DP 288         // padded stride (multiple of 16)
#define NFEAT 9
#define NVOC 128
#define NLAY 5
#define NPG 64
#define NGRAPH 2048
#define BN_EPS 1e-5f
#define BM 128
#define BK 32
#define NEPAD (NE + 3 * NN)   // max padded edge count
#define LDSE 1280             // per-block staged edge indices (32 nodes)

typedef unsigned short u16;
typedef __attribute__((ext_vector_type(8))) short s16x8;
typedef __attribute__((ext_vector_type(4))) float f32x4;

__device__ __forceinline__ float bf2f(u16 u) {
  union { unsigned int i; float f; } x; x.i = ((unsigned int)u) << 16; return x.f;
}
__device__ __forceinline__ u16 f2bf(float f) {
  union { float f; unsigned int i; } x; x.f = f;
  unsigned int r = x.i + 0x7fffu + ((x.i >> 16) & 1u);
  return (u16)(r >> 16);
}
__device__ __forceinline__ void acc4(float* a, uint2 m) {
  a[0] += bf2f((u16)m.x); a[1] += bf2f((u16)(m.x >> 16));
  a[2] += bf2f((u16)m.y); a[3] += bf2f((u16)(m.y >> 16));
}

// ---------------- graph preprocessing ----------------

__global__ void hist_kernel(const int* __restrict__ ei, int* __restrict__ cnt) {
  int e = blockIdx.x * 256 + threadIdx.x;
  if (e < NE) atomicAdd(&cnt[ei[NE + e]], 1);
}

__global__ void pad_dinv_kernel(const int* __restrict__ cnt, int* __restrict__ cnt_pad,
                                float* __restrict__ dinv) {
  int v = blockIdx.x * 256 + threadIdx.x;
  if (v < NN) {
    int c = cnt[v];
    cnt_pad[v] = (c + 3) & ~3;
    dinv[v] = rsqrtf(1.0f + (float)c);
  }
}

__global__ void scan_block_kernel(const int* __restrict__ in, int* __restrict__ out_ex,
                                  int* __restrict__ partials) {
  __shared__ int buf[2][1024];
  int t = threadIdx.x;
  int idx = blockIdx.x * 1024 + t;
  int v = in[idx];
  buf[0][t] = v;
  __syncthreads();
  int cur = 0;
  for (int off = 1; off < 1024; off <<= 1) {
    int x = buf[cur][t];
    if (t >= off) x += buf[cur][t - off];
    buf[cur ^ 1][t] = x;
    __syncthreads();
    cur ^= 1;
  }
  out_ex[idx] = buf[cur][t] - v;
  if (t == 1023) partials[blockIdx.x] = buf[cur][t];
}

__global__ void scan_partials_kernel(int* partials) {
  __shared__ int buf[2][128];
  int t = threadIdx.x;
  int v = partials[t];
  buf[0][t] = v;
  __syncthreads();
  int cur = 0;
  for (int off = 1; off < 128; off <<= 1) {
    int x = buf[cur][t];
    if (t >= off) x += buf[cur][t - off];
    buf[cur ^ 1][t] = x;
    __syncthreads();
    cur ^= 1;
  }
  partials[t] = buf[cur][t] - v;
}

__global__ void add_offsets_kernel(int* __restrict__ indptr, const int* __restrict__ partials,
                                   int* __restrict__ cursor, const int* __restrict__ cnt_pad) {
  int i = blockIdx.x * 256 + threadIdx.x;
  if (i < NN) {
    int v = indptr[i] + partials[i >> 10];
    indptr[i] = v;
    cursor[i] = v;
    if (i == NN - 1) indptr[NN] = v + cnt_pad[NN - 1];
  }
}

__global__ void fill_csr_kernel(const int* __restrict__ ei, int* __restrict__ cursor,
                                int* __restrict__ srcs) {
  int e = blockIdx.x * 256 + threadIdx.x;
  if (e < NE) {
    int c = ei[NE + e];
    int p = atomicAdd(&cursor[c], 1);
    srcs[p] = ei[e];
  }
}

// pad slots point at the all-zeros row NN
__global__ void pad_fill_kernel(const int* __restrict__ cursor, const int* __restrict__ indptr,
                                int* __restrict__ srcs) {
  int v = blockIdx.x * 256 + threadIdx.x;
  if (v < NN) {
    int pe = indptr[v + 1];
    for (int p = cursor[v]; p < pe; ++p) srcs[p] = NN;
  }
}

__global__ void zrow_kernel(u16* __restrict__ P, u16* __restrict__ Q) {
  int i = threadIdx.x;
  if (i < DP) {
    P[(size_t)NN * DP + i] = 0;
    Q[(size_t)NN * DP + i] = 0;
  }
}

__global__ void wpad_kernel(const float* __restrict__ convW, const float* __restrict__ postW,
                            u16* __restrict__ Wp) {
  int i = blockIdx.x * 256 + threadIdx.x;
  const int total = 6 * 320 * DP;
  if (i >= total) return;
  int k = i % DP;
  int r = i / DP;
  int j = r % 320;
  int m = r / 320;
  float val = 0.f;
  if (j < DIM && k < DIM)
    val = (m < 5) ? convW[((size_t)m * DIM + j) * DIM + k] : postW[(size_t)j * DIM + k];
  Wp[i] = f2bf(val);
}

// ---------------- atom encoder ----------------

__global__ void embed_kernel(const int* __restrict__ xa, const float* __restrict__ emb,
                             u16* __restrict__ P) {
  int n = blockIdx.x;
  int idx[NFEAT];
#pragma unroll
  for (int f = 0; f < NFEAT; ++f) idx[f] = xa[n * NFEAT + f];
  for (int d = threadIdx.x; d < DP; d += 128) {
    float s = 0.f;
    if (d < DIM) {
#pragma unroll
      for (int f = 0; f < NFEAT; ++f) s += emb[((size_t)f * NVOC + idx[f]) * DIM + d];
    }
    P[(size_t)n * DP + d] = f2bf(s);
  }
}

// ---------------- MFMA GEMM (BM=128, col tile 160, 2 col passes) ----------------

__device__ __forceinline__ uint4 xform8(uint4 r, const float* __restrict__ sc,
                                        const float* __restrict__ sh, int k) {
  union { uint4 u; u16 h[8]; } in, out;
  in.u = r;
#pragma unroll
  for (int j = 0; j < 8; ++j) {
    float x = fmaf(bf2f(in.h[j]), sc[k + j], sh[k + j]);
    out.h[j] = f2bf(fmaxf(x, 0.f));
  }
  return out.u;
}

__launch_bounds__(256)
__global__ void gemm_kernel(const u16* __restrict__ A, const u16* __restrict__ Wp,
                            u16* __restrict__ C,
                            const float* __restrict__ scale, const float* __restrict__ shift,
                            const float* __restrict__ rowscale, const float* __restrict__ colbias) {
  __shared__ __align__(16) u16 Asl[BM * BK];     // 8 KB
  __shared__ __align__(16) u16 Bsl[160 * BK];    // 10 KB
  const int tid = threadIdx.x;
  const int lane = tid & 63;
  const int wv = tid >> 6, wm = wv & 1, wn = wv >> 1;   // waves 2(M) x 2(N)
  const int b = blockIdx.x;
  const int grp = b >> 4, rem = b & 15;
  const int col = rem >> 3, pan8 = rem & 7;
  const int row0 = (grp * 8 + pan8) * BM, col0 = col * 128;

  const int sr = tid >> 2, ssl = tid & 3;
  const int swz = ((ssl ^ (sr & 3) ^ ((sr >> 2) & 3)) << 3);
  const int aw0 = sr * BK + swz;
  const u16* ag0 = A + (size_t)(row0 + sr) * DP + ssl * 8;
  const u16* ag1 = ag0 + (size_t)64 * DP;
  const u16* bg0 = Wp + (size_t)(col0 + sr) * DP + ssl * 8;
  const u16* bg1 = bg0 + (size_t)64 * DP;
  const u16* bg2 = bg0 + (size_t)128 * DP;
  const bool st2 = (tid < 128);

  const int fr = lane & 15, fs = lane >> 4;
  const int fswz = ((fs ^ (fr & 3) ^ ((fr >> 2) & 3)) << 3);
  int aoff[4], boff[5];
#pragma unroll
  for (int i = 0; i < 4; ++i) aoff[i] = (wm * 64 + i * 16 + fr) * BK + fswz;
#pragma unroll
  for (int j = 0; j < 5; ++j) boff[j] = (wn * 80 + j * 16 + fr) * BK + fswz;

  const bool bn = (scale != nullptr);
  const int NS = DP / BK;

  {
    uint4 ra0 = *(const uint4*)(ag0);
    uint4 ra1 = *(const uint4*)(ag1);
    uint4 rb0 = *(const uint4*)(bg0);
    uint4 rb1 = *(const uint4*)(bg1);
    uint4 rb2;
    if (st2) rb2 = *(const uint4*)(bg2);
    if (bn) {
      ra0 = xform8(ra0, scale, shift, ssl * 8);
      ra1 = xform8(ra1, scale, shift, ssl * 8);
    }
    *(uint4*)&Asl[aw0] = ra0;
    *(uint4*)&Asl[aw0 + 64 * BK] = ra1;
    *(uint4*)&Bsl[aw0] = rb0;
    *(uint4*)&Bsl[aw0 + 64 * BK] = rb1;
    if (st2) *(uint4*)&Bsl[aw0 + 128 * BK] = rb2;
  }
  __syncthreads();

  f32x4 acc[4][5];
#pragma unroll
  for (int i = 0; i < 4; ++i)
#pragma unroll
    for (int j = 0; j < 5; ++j) acc[i][j] = (f32x4){0.f, 0.f, 0.f, 0.f};

  for (int s = 0; s < NS; ++s) {
    const bool more = (s < NS - 1);
    uint4 na0, na1, nb0, nb1, nb2;
    if (more) {
      na0 = *(const uint4*)(ag0 + (s + 1) * BK);
      na1 = *(const uint4*)(ag1 + (s + 1) * BK);
      nb0 = *(const uint4*)(bg0 + (s + 1) * BK);
      nb1 = *(const uint4*)(bg1 + (s + 1) * BK);
      if (st2) nb2 = *(const uint4*)(bg2 + (s + 1) * BK);
    }
    s16x8 af[4], bf[5];
#pragma unroll
    for (int i = 0; i < 4; ++i) af[i] = *(const s16x8*)&Asl[aoff[i]];
#pragma unroll
    for (int j = 0; j < 5; ++j) bf[j] = *(const s16x8*)&Bsl[boff[j]];
#pragma unroll
    for (int i = 0; i < 4; ++i)
#pragma unroll
      for (int j = 0; j < 5; ++j)
        acc[i][j] = __builtin_amdgcn_mfma_f32_16x16x32_bf16(af[i], bf[j], acc[i][j], 0, 0, 0);
    if (more) {
      __syncthreads();
      int k2 = (s + 1) * BK + ssl * 8;
      if (bn) {
        na0 = xform8(na0, scale, shift, k2);
        na1 = xform8(na1, scale, shift, k2);
      }
      *(uint4*)&Asl[aw0] = na0;
      *(uint4*)&Asl[aw0 + 64 * BK] = na1;
      *(uint4*)&Bsl[aw0] = nb0;
      *(uint4*)&Bsl[aw0 + 64 * BK] = nb1;
      if (st2) *(uint4*)&Bsl[aw0 + 128 * BK] = nb2;
      __syncthreads();
    }
  }

#pragma unroll
  for (int i = 0; i < 4; ++i) {
    int gr0 = row0 + wm * 64 + i * 16 + fs * 4;
    float rs[4];
#pragma unroll
    for (int r = 0; r < 4; ++r) rs[r] = rowscale ? rowscale[gr0 + r] : 1.f;
#pragma unroll
    for (int j = 0; j < 5; ++j) {
      int gc = col0 + wn * 80 + j * 16 + fr;
      if (gc < DP) {
        float cb = (colbias && gc < DIM) ? colbias[gc] : 0.f;
#pragma unroll
        for (int r = 0; r < 4; ++r) {
          u16 o = (gc < DIM) ? f2bf(fmaf(acc[i][j][r], rs[r], cb)) : (u16)0;
          C[(size_t)(gr0 + r) * DP + gc] = o;
        }
      }
    }
  }
}

// ---------------- SpMM v5: natural-order quad-interleave ----------------
// Block = 32 nodes (4096 blocks, fine-grained balance). Each wave: 8 nodes as
// 2 quads of consecutive nodes -> 16 independent c0 gathers in flight. Padded
// edges hit the L1-hot zero row; predication waste on unequal quads is cheap.

__launch_bounds__(256)
__global__ void spmm_kernel(const u16* __restrict__ X, u16* __restrict__ Y,
                            const int* __restrict__ indptr, const int* __restrict__ srcs,
                            const float* __restrict__ dinv, const float* __restrict__ bias,
                            float* __restrict__ bn_sum, float* __restrict__ bn_sq) {
  __shared__ float ls[DP], lq[DP];
  __shared__ int sptr[33];
  __shared__ int sidx[LDSE];
  int tid = threadIdx.x;
  for (int i = tid; i < DP; i += 256) { ls[i] = 0.f; lq[i] = 0.f; }
  int vb = blockIdx.x * 32;
  if (tid < 33) sptr[tid] = indptr[vb + tid];
  __syncthreads();
  int ebase = sptr[0];
  int ecnt = sptr[32] - ebase;
  const int* ip;
  if (ecnt <= LDSE) {
    for (int i = tid; i < ecnt; i += 256) sidx[i] = srcs[ebase + i];
    ip = sidx;
  } else {
    ip = srcs + ebase;
  }
  __syncthreads();

  int lane = tid & 63, wv = tid >> 6;
  int c0 = lane << 2;
  int c1 = 256 + (lane << 2);
  bool tl = lane < 8;
  float bia[4], bib[4];
#pragma unroll
  for (int j = 0; j < 4; ++j) bia[j] = bias[c0 + j];
#pragma unroll
  for (int j = 0; j < 4; ++j) bib[j] = (tl && c1 + j < DIM) ? bias[c1 + j] : 0.f;
  float s0[4] = {}, q0[4] = {}, s1[4] = {}, q1[4] = {};

  for (int g = 0; g < 2; ++g) {
    int nb = wv * 8 + g * 4;       // local index of quad start
    int eb[4], ne[4];
#pragma unroll
    for (int j = 0; j < 4; ++j) {
      eb[j] = sptr[nb + j] - ebase;
      ne[j] = sptr[nb + j + 1] - sptr[nb + j];
    }
    int nemax = max(max(ne[0], ne[1]), max(ne[2], ne[3]));
    const u16* xs[4];
#pragma unroll
    for (int j = 0; j < 4; ++j) xs[j] = X + (size_t)(vb + nb + j) * DP;
    float A0[4][4] = {}, A1[4][4] = {};
    {
      uint2 ms[4];
#pragma unroll
      for (int j = 0; j < 4; ++j) ms[j] = *(const uint2*)(xs[j] + c0);
#pragma unroll
      for (int j = 0; j < 4; ++j) acc4(A0[j], ms[j]);
      if (tl) {
        uint2 ts[4];
#pragma unroll
        for (int j = 0; j < 4; ++j) ts[j] = *(const uint2*)(xs[j] + c1);
#pragma unroll
        for (int j = 0; j < 4; ++j) acc4(A1[j], ts[j]);
      }
    }
    for (int e = 0; e < nemax; e += 4) {
      const u16* p[4][4];
#pragma unroll
      for (int j = 0; j < 4; ++j) {
        bool av = e < ne[j];
        int o = av ? eb[j] + e : 0;
#pragma unroll
        for (int k = 0; k < 4; ++k) {
          int t = ip[o + k];
          p[j][k] = X + (size_t)(av ? t : NN) * DP;
        }
      }
      uint2 m[4][4];
#pragma unroll
      for (int j = 0; j < 4; ++j)
#pragma unroll
        for (int k = 0; k < 4; ++k) m[j][k] = *(const uint2*)(p[j][k] + c0);
#pragma unroll
      for (int j = 0; j < 4; ++j)
#pragma unroll
        for (int k = 0; k < 4; ++k) acc4(A0[j], m[j][k]);
      if (tl) {
        uint2 t[4][4];
#pragma unroll
        for (int j = 0; j < 4; ++j)
#pragma unroll
          for (int k = 0; k < 4; ++k) t[j][k] = *(const uint2*)(p[j][k] + c1);
#pragma unroll
        for (int j = 0; j < 4; ++j)
#pragma unroll
          for (int k = 0; k < 4; ++k) acc4(A1[j], t[j][k]);
      }
    }
#pragma unroll
    for (int j = 0; j < 4; ++j) {
      int v = vb + nb + j;
      float dv = dinv[v];
      u16* yv = Y + (size_t)v * DP;
      float y[4];
#pragma unroll
      for (int q = 0; q < 4; ++q) {
        y[q] = fmaf(dv, A0[j][q], bia[q]);
        s0[q] += y[q]; q0[q] += y[q] * y[q];
      }
      uint2 wo;
      wo.x = (unsigned)f2bf(y[0]) | ((unsigned)f2bf(y[1]) << 16);
      wo.y = (unsigned)f2bf(y[2]) | ((unsigned)f2bf(y[3]) << 16);
      *(uint2*)(yv + c0) = wo;
      if (tl) {
        float z[4];
#pragma unroll
        for (int q = 0; q < 4; ++q) {
          z[q] = fmaf(dv, A1[j][q], bib[q]);
          s1[q] += z[q]; q1[q] += z[q] * z[q];
        }
        uint2 w2;
        w2.x = (unsigned)f2bf(z[0]) | ((unsigned)f2bf(z[1]) << 16);
        w2.y = (unsigned)f2bf(z[2]) | ((unsigned)f2bf(z[3]) << 16);
        *(uint2*)(yv + c1) = w2;
      }
    }
  }

#pragma unroll
  for (int j = 0; j < 4; ++j) { atomicAdd(&ls[c0 + j], s0[j]); atomicAdd(&lq[c0 + j], q0[j]); }
  if (tl) {
#pragma unroll
    for (int j = 0; j < 4; ++j) { atomicAdd(&ls[c1 + j], s1[j]); atomicAdd(&lq[c1 + j], q1[j]); }
  }
  __syncthreads();
  for (int i = tid; i < DP; i += 256) {
    atomicAdd(&bn_sum[i], ls[i]);
    atomicAdd(&bn_sq[i], lq[i]);
  }
}

__global__ void bn_finalize_kernel(const float* __restrict__ bn_sum, const float* __restrict__ bn_sq,
                                   const float* __restrict__ gamma, const float* __restrict__ beta,
                                   float* __restrict__ scale, float* __restrict__ shift) {
  int d = threadIdx.x;
  if (d >= DP) return;
  if (d < DIM) {
    const float invN = 1.0f / (float)NN;
    float mu = bn_sum[d] * invN;
    float var = bn_sq[d] * invN - mu * mu;
    float rstd = rsqrtf(var + BN_EPS);
    float sc = gamma[d] * rstd;
    scale[d] = sc;
    shift[d] = fmaf(-mu, sc, beta[d]);
  } else {
    scale[d] = 0.f;
    shift[d] = 0.f;
  }
}

// ---------------- MFMA Gram decode ----------------

__launch_bounds__(256)
__global__ void decode_kernel(const u16* __restrict__ H, float* __restrict__ out) {
  __shared__ __align__(16) u16 tile[4][2][NPG * BK];
  int tid = threadIdx.x, lane = tid & 63, wv = tid >> 6;
  int g = blockIdx.x * 4 + wv;
  const u16* Hg = H + (size_t)g * NPG * DP;
  const int ssl = lane & 3;
  int soff[4];
  const u16* sg[4];
#pragma unroll
  for (int i = 0; i < 4; ++i) {
    int r = (lane >> 2) + i * 16;
    soff[i] = r * BK + ((ssl ^ (r & 3) ^ ((r >> 2) & 3)) << 3);
    sg[i] = Hg + (size_t)r * DP + ssl * 8;
  }
  const int fr = lane & 15, fs = lane >> 4;
  const int fswz = ((fs ^ (fr & 3) ^ ((fr >> 2) & 3)) << 3);
  int foff[4];
#pragma unroll
  for (int i = 0; i < 4; ++i) foff[i] = (i * 16 + fr) * BK + fswz;

  u16* t0 = tile[wv][0];
  u16* t1 = tile[wv][1];
  uint4 rg[4];
#pragma unroll
  for (int i = 0; i < 4; ++i) rg[i] = *(const uint4*)(sg[i]);
#pragma unroll
  for (int i = 0; i < 4; ++i) *(uint4*)&t0[soff[i]] = rg[i];

  f32x4 acc[4][4];
#pragma unroll
  for (int i = 0; i < 4; ++i)
#pragma unroll
    for (int j = 0; j < 4; ++j) acc[i][j] = (f32x4){0.f, 0.f, 0.f, 0.f};

  for (int s = 0; s < DP / BK; ++s) {
    u16* cur = (s & 1) ? t1 : t0;
    u16* nxt = (s & 1) ? t0 : t1;
    const bool more = (s < DP / BK - 1);
    if (more) {
#pragma unroll
      for (int i = 0; i < 4; ++i) rg[i] = *(const uint4*)(sg[i] + (s + 1) * BK);
    }
    s16x8 af[4];
#pragma unroll
    for (int i = 0; i < 4; ++i) af[i] = *(const s16x8*)&cur[foff[i]];
#pragma unroll
    for (int i = 0; i < 4; ++i)
#pragma unroll
      for (int j = 0; j < 4; ++j)
        acc[i][j] = __builtin_amdgcn_mfma_f32_16x16x32_bf16(af[i], af[j], acc[i][j], 0, 0, 0);
    if (more) {
#pragma unroll
      for (int i = 0; i < 4; ++i) *(uint4*)&nxt[soff[i]] = rg[i];
    }
  }
  float* og = out + (size_t)g * NPG * NPG;
#pragma unroll
  for (int i = 0; i < 4; ++i) {
    int m0 = i * 16 + fs * 4;
#pragma unroll
    for (int j = 0; j < 4; ++j) {
      int n = j * 16 + fr;
#pragma unroll
      for (int r = 0; r < 4; ++r) og[(m0 + r) * NPG + n] = acc[i][j][r];
    }
  }
}

// ---------------- launch ----------------

extern "C" void kernel_launch(void* const* d_in, const int* in_sizes, int n_in,
                              void* d_out, int out_size, void* d_ws, size_t ws_size,
                              hipStream_t stream) {
  const int* xa = (const int*)d_in[0];
  const int* ei = (const int*)d_in[1];
  const float* emb = (const float*)d_in[2];
  const float* convW = (const float*)d_in[3];
  const float* convB = (const float*)d_in[4];
  const float* gamma = (const float*)d_in[5];
  const float* beta = (const float*)d_in[6];
  const float* postW = (const float*)d_in[7];
  const float* postB = (const float*)d_in[8];
  float* out = (float*)d_out;

  char* w = (char*)d_ws;
  u16* P = (u16*)w;          w += (size_t)(NN + 1) * DP * sizeof(u16);
  u16* Q = (u16*)w;          w += (size_t)(NN + 1) * DP * sizeof(u16);
  u16* Wp = (u16*)w;         w += (size_t)6 * 320 * DP * sizeof(u16);
  float* dinv = (float*)w;   w += (size_t)NN * sizeof(float);
  int* cnt = (int*)w;        w += (size_t)NN * sizeof(int);
  int* cnt_pad = (int*)w;    w += (size_t)NN * sizeof(int);
  int* indptr = (int*)w;     w += (size_t)(NN + 64) * sizeof(int);
  int* cursor = (int*)w;     w += (size_t)NN * sizeof(int);
  int* srcs = (int*)w;       w += (size_t)NEPAD * sizeof(int);
  int* partials = (int*)w;   w += 256 * sizeof(int);
  float* bn_sum = (float*)w; w += DP * sizeof(float);
  float* bn_sq = (float*)w;  w += DP * sizeof(float);
  float* bnscale = (float*)w; w += DP * sizeof(float);
  float* bnshift = (float*)w; w += DP * sizeof(float);

  size_t need = (size_t)(w - (char*)d_ws);
  if (ws_size < need) return;

  hipMemsetAsync(cnt, 0, (size_t)NN * sizeof(int), stream);
  hist_kernel<<<NE / 256, 256, 0, stream>>>(ei, cnt);
  pad_dinv_kernel<<<NN / 256, 256, 0, stream>>>(cnt, cnt_pad, dinv);
  scan_block_kernel<<<NN / 1024, 1024, 0, stream>>>(cnt_pad, indptr, partials);
  scan_partials_kernel<<<1, 128, 0, stream>>>(partials);
  add_offsets_kernel<<<NN / 256, 256, 0, stream>>>(indptr, partials, cursor, cnt_pad);
  fill_csr_kernel<<<NE / 256, 256, 0, stream>>>(ei, cursor, srcs);
  pad_fill_kernel<<<NN / 256, 256, 0, stream>>>(cursor, indptr, srcs);
  wpad_kernel<<<(6 * 320 * DP + 255) / 256, 256, 0, stream>>>(convW, postW, Wp);
  embed_kernel<<<NN, 128, 0, stream>>>(xa, emb, P);
  zrow_kernel<<<1, 288, 0, stream>>>(P, Q);

  for (int l = 0; l < NLAY; ++l) {
    gemm_kernel<<<(NN / BM) * 2, 256, 0, stream>>>(
        P, Wp + (size_t)l * 320 * DP, Q,
        l ? bnscale : nullptr, l ? bnshift : nullptr, dinv, nullptr);
    hipMemsetAsync(bn_sum, 0, 2 * DP * sizeof(float), stream);
    spmm_kernel<<<NN / 32, 256, 0, stream>>>(Q, P, indptr, srcs, dinv,
                                             convB + (size_t)l * DIM, bn_sum, bn_sq);
    bn_finalize_kernel<<<1, DP, 0, stream>>>(bn_sum, bn_sq, gamma + (size_t)l * DIM,
                                             beta + (size_t)l * DIM, bnscale, bnshift);
  }

  gemm_kernel<<<(NN / BM) * 2, 256, 0, stream>>>(
      P, Wp + (size_t)5 * 320 * DP, Q, bnscale, bnshift, nullptr, postB);

  decode_kernel<<<NGRAPH / 4, 256, 0, stream>>>(Q, out);
}

// Round 9
// 1216.672 us; speedup vs baseline: 2.7828x; 1.0538x over previous
//
#include <hip/hip_runtime.h>
#include <hip/hip_bf16.h>
#include <cstdint>

#define NN 131072      // nodes
#define NE 524288      // directed edges
#define DIM 275        // feature dim
#define DP 288         // padded stride (multiple of 16)
#define NFEAT 9
#define NVOC 128
#define NLAY 5
#define NPG 64
#define NGRAPH 2048
#define BN_EPS 1e-5f
#define BK 32
#define NEPAD (NE + 3 * NN)   // max padded edge count
#define LDSE 1536             // per-block staged edge indices (64 nodes)

typedef unsigned short u16;
typedef __attribute__((ext_vector_type(8))) short s16x8;
typedef __attribute__((ext_vector_type(4))) float f32x4;

__device__ __forceinline__ float bf2f(u16 u) {
  union { unsigned int i; float f; } x; x.i = ((unsigned int)u) << 16; return x.f;
}
__device__ __forceinline__ u16 f2bf(float f) {
  union { float f; unsigned int i; } x; x.f = f;
  unsigned int r = x.i + 0x7fffu + ((x.i >> 16) & 1u);
  return (u16)(r >> 16);
}
__device__ __forceinline__ void acc4(float* a, uint2 m) {
  a[0] += bf2f((u16)m.x); a[1] += bf2f((u16)(m.x >> 16));
  a[2] += bf2f((u16)m.y); a[3] += bf2f((u16)(m.y >> 16));
}

// ---------------- graph preprocessing ----------------

__global__ void hist_kernel(const int* __restrict__ ei, int* __restrict__ cnt) {
  int e = blockIdx.x * 256 + threadIdx.x;
  if (e < NE) atomicAdd(&cnt[ei[NE + e]], 1);
}

__global__ void pad_dinv_kernel(const int* __restrict__ cnt, int* __restrict__ cnt_pad,
                                float* __restrict__ dinv) {
  int v = blockIdx.x * 256 + threadIdx.x;
  if (v < NN) {
    int c = cnt[v];
    cnt_pad[v] = (c + 3) & ~3;
    dinv[v] = rsqrtf(1.0f + (float)c);
  }
}

__global__ void scan_block_kernel(const int* __restrict__ in, int* __restrict__ out_ex,
                                  int* __restrict__ partials) {
  __shared__ int buf[2][1024];
  int t = threadIdx.x;
  int idx = blockIdx.x * 1024 + t;
  int v = in[idx];
  buf[0][t] = v;
  __syncthreads();
  int cur = 0;
  for (int off = 1; off < 1024; off <<= 1) {
    int x = buf[cur][t];
    if (t >= off) x += buf[cur][t - off];
    buf[cur ^ 1][t] = x;
    __syncthreads();
    cur ^= 1;
  }
  out_ex[idx] = buf[cur][t] - v;
  if (t == 1023) partials[blockIdx.x] = buf[cur][t];
}

__global__ void scan_partials_kernel(int* partials) {
  __shared__ int buf[2][128];
  int t = threadIdx.x;
  int v = partials[t];
  buf[0][t] = v;
  __syncthreads();
  int cur = 0;
  for (int off = 1; off < 128; off <<= 1) {
    int x = buf[cur][t];
    if (t >= off) x += buf[cur][t - off];
    buf[cur ^ 1][t] = x;
    __syncthreads();
    cur ^= 1;
  }
  partials[t] = buf[cur][t] - v;
}

__global__ void add_offsets_kernel(int* __restrict__ indptr, const int* __restrict__ partials,
                                   int* __restrict__ cursor, const int* __restrict__ cnt_pad) {
  int i = blockIdx.x * 256 + threadIdx.x;
  if (i < NN) {
    int v = indptr[i] + partials[i >> 10];
    indptr[i] = v;
    cursor[i] = v;
    if (i == NN - 1) indptr[NN] = v + cnt_pad[NN - 1];
  }
}

__global__ void fill_csr_kernel(const int* __restrict__ ei, int* __restrict__ cursor,
                                int* __restrict__ srcs) {
  int e = blockIdx.x * 256 + threadIdx.x;
  if (e < NE) {
    int c = ei[NE + e];
    int p = atomicAdd(&cursor[c], 1);
    srcs[p] = ei[e];
  }
}

// pad slots point at the all-zeros row NN
__global__ void pad_fill_kernel(const int* __restrict__ cursor, const int* __restrict__ indptr,
                                int* __restrict__ srcs) {
  int v = blockIdx.x * 256 + threadIdx.x;
  if (v < NN) {
    int pe = indptr[v + 1];
    for (int p = cursor[v]; p < pe; ++p) srcs[p] = NN;
  }
}

__global__ void zrow_kernel(u16* __restrict__ P, u16* __restrict__ Q) {
  int i = threadIdx.x;
  if (i < DP) {
    P[(size_t)NN * DP + i] = 0;
    Q[(size_t)NN * DP + i] = 0;
  }
}

__global__ void wpad_kernel(const float* __restrict__ convW, const float* __restrict__ postW,
                            u16* __restrict__ Wp) {
  int i = blockIdx.x * 256 + threadIdx.x;
  const int total = 6 * 320 * DP;
  if (i >= total) return;
  int k = i % DP;
  int r = i / DP;
  int j = r % 320;
  int m = r / 320;
  float val = 0.f;
  if (j < DIM && k < DIM)
    val = (m < 5) ? convW[((size_t)m * DIM + j) * DIM + k] : postW[(size_t)j * DIM + k];
  Wp[i] = f2bf(val);
}

// ---------------- atom encoder ----------------

__global__ void embed_kernel(const int* __restrict__ xa, const float* __restrict__ emb,
                             u16* __restrict__ P) {
  int n = blockIdx.x;
  int idx[NFEAT];
#pragma unroll
  for (int f = 0; f < NFEAT; ++f) idx[f] = xa[n * NFEAT + f];
  for (int d = threadIdx.x; d < DP; d += 128) {
    float s = 0.f;
    if (d < DIM) {
#pragma unroll
      for (int f = 0; f < NFEAT; ++f) s += emb[((size_t)f * NVOC + idx[f]) * DIM + d];
    }
    P[(size_t)n * DP + d] = f2bf(s);
  }
}

// ---------------- MFMA GEMM v3: single full-width col pass ----------------
// Block = 128 rows x 288 cols, 4 waves; wave = 32 rows (2 row-frags) x 18
// col-frags; acc = 36 f32x4. A: direct per-lane global loads (each 64B line
// = exactly one BK chunk of one row -> pure stream), 1-step reg prefetch,
// BN+ReLU applied in-register. B (weights, L2-resident): staged to LDS per
// K-step, double-buffered, 80B row stride (2-way banks = free). Each B-frag
// ds_read feeds 2 MFMAs. One barrier per K-step.

__device__ __forceinline__ uint4 xform8(uint4 r, const float* __restrict__ sc,
                                        const float* __restrict__ sh, int k) {
  union { uint4 u; u16 h[8]; } in, out;
  in.u = r;
#pragma unroll
  for (int j = 0; j < 8; ++j) {
    float x = fmaf(bf2f(in.h[j]), sc[k + j], sh[k + j]);
    out.h[j] = f2bf(fmaxf(x, 0.f));
  }
  return out.u;
}

__launch_bounds__(256)
__global__ void gemm_kernel(const u16* __restrict__ A, const u16* __restrict__ Wp,
                            u16* __restrict__ C,
                            const float* __restrict__ scale, const float* __restrict__ shift,
                            const float* __restrict__ rowscale, const float* __restrict__ colbias) {
  __shared__ __align__(16) u16 Bs[2][320 * 40];   // 80B row stride, 2x25.6KB
  const int tid = threadIdx.x, lane = tid & 63, wv = tid >> 6;
  const int lr = lane & 15, lk = lane >> 4;
  const int row0 = blockIdx.x * 128 + wv * 32;
  const u16* ag0 = A + (size_t)(row0 + lr) * DP + lk * 8;
  const u16* ag1 = ag0 + (size_t)16 * DP;
  // B staging: thread t covers rows (t>>2)+64i (i=0..4), 16B chunk t&3
  const int srow = tid >> 2, schk = tid & 3;
  const u16* sg = Wp + (size_t)srow * DP + schk * 8;
  const int swoff = srow * 40 + schk * 8;
  // B frag base: row j*16+lr, chunk lk -> boff = j*640 + (lr*40 + lk*8)
  const int bbase = lr * 40 + lk * 8;
  const bool bn = (scale != nullptr);

  // prologue: stage B for s=0, load A for s=0
#pragma unroll
  for (int i = 0; i < 5; ++i) {
    uint4 rb = *(const uint4*)(sg + (size_t)(64 * i) * DP);
    *(uint4*)&Bs[0][swoff + 64 * i * 40] = rb;
  }
  uint4 a0 = *(const uint4*)(ag0);
  uint4 a1 = *(const uint4*)(ag1);
  __syncthreads();

  f32x4 acc0[18], acc1[18];
#pragma unroll
  for (int j = 0; j < 18; ++j) {
    acc0[j] = (f32x4){0.f, 0.f, 0.f, 0.f};
    acc1[j] = (f32x4){0.f, 0.f, 0.f, 0.f};
  }

#pragma unroll 1
  for (int s = 0; s < 9; ++s) {
    const bool more = (s < 8);
    uint4 n0, n1, nb0, nb1, nb2, nb3, nb4;
    if (more) {   // issue next-step loads early (T14): A from HBM, B from L2
      int k = (s + 1) * BK;
      nb0 = *(const uint4*)(sg + k);
      nb1 = *(const uint4*)(sg + (size_t)64 * DP + k);
      nb2 = *(const uint4*)(sg + (size_t)128 * DP + k);
      nb3 = *(const uint4*)(sg + (size_t)192 * DP + k);
      nb4 = *(const uint4*)(sg + (size_t)256 * DP + k);
      n0 = *(const uint4*)(ag0 + k);
      n1 = *(const uint4*)(ag1 + k);
    }
    if (bn) {
      int kk = s * BK + lk * 8;
      a0 = xform8(a0, scale, shift, kk);
      a1 = xform8(a1, scale, shift, kk);
    }
    union { uint4 u; s16x8 v; } ca, cb;
    ca.u = a0; s16x8 af0 = ca.v;
    cb.u = a1; s16x8 af1 = cb.v;
    const u16* bp = &Bs[s & 1][bbase];
#pragma unroll
    for (int j = 0; j < 18; ++j) {
      s16x8 bf = *(const s16x8*)&bp[j * 640];
      acc0[j] = __builtin_amdgcn_mfma_f32_16x16x32_bf16(af0, bf, acc0[j], 0, 0, 0);
      acc1[j] = __builtin_amdgcn_mfma_f32_16x16x32_bf16(af1, bf, acc1[j], 0, 0, 0);
    }
    if (more) {
      u16* bq = &Bs[(s + 1) & 1][swoff];
      *(uint4*)&bq[0] = nb0;
      *(uint4*)&bq[64 * 40] = nb1;
      *(uint4*)&bq[128 * 40] = nb2;
      *(uint4*)&bq[192 * 40] = nb3;
      *(uint4*)&bq[256 * 40] = nb4;
      a0 = n0; a1 = n1;
    }
    __syncthreads();
  }

  // epilogue: D row = i*16 + lk*4 + r, col = j*16 + lr
#pragma unroll
  for (int i = 0; i < 2; ++i) {
    int gr0 = row0 + i * 16 + lk * 4;
    float rs[4];
#pragma unroll
    for (int r = 0; r < 4; ++r) rs[r] = rowscale ? rowscale[gr0 + r] : 1.f;
#pragma unroll
    for (int j = 0; j < 18; ++j) {
      f32x4 av = i ? acc1[j] : acc0[j];
      int gc = j * 16 + lr;
      float cb = (colbias && gc < DIM) ? colbias[gc] : 0.f;
#pragma unroll
      for (int r = 0; r < 4; ++r) {
        u16 o = (gc < DIM) ? f2bf(fmaf(av[r], rs[r], cb)) : (u16)0;
        C[(size_t)(gr0 + r) * DP + gc] = o;
      }
    }
  }
}

// ---------------- SpMM (r6 config, 103us): LDS idx + pair-interleave ----------------

__launch_bounds__(256)
__global__ void spmm_kernel(const u16* __restrict__ X, u16* __restrict__ Y,
                            const int* __restrict__ indptr, const int* __restrict__ srcs,
                            const float* __restrict__ dinv, const float* __restrict__ bias,
                            float* __restrict__ bn_sum, float* __restrict__ bn_sq) {
  __shared__ float ls[DP], lq[DP];
  __shared__ int sptr[65];
  __shared__ int sidx[LDSE];
  int tid = threadIdx.x;
  for (int i = tid; i < DP; i += 256) { ls[i] = 0.f; lq[i] = 0.f; }
  int vb = blockIdx.x * 64;
  if (tid < 65) sptr[tid] = indptr[vb + tid];
  __syncthreads();
  int ebase = sptr[0];
  int ecnt = sptr[64] - ebase;
  const int* ip;   // generic pointer: LDS fast path, global fallback
  if (ecnt <= LDSE) {
    for (int i = tid; i < ecnt; i += 256) sidx[i] = srcs[ebase + i];
    ip = sidx;
  } else {
    ip = srcs + ebase;
  }
  __syncthreads();

  int lane = tid & 63, wv = tid >> 6;
  int c0 = lane << 2;
  int c1 = 256 + (lane << 2);
  bool tl = lane < 8;
  float bia[4], bib[4];
#pragma unroll
  for (int j = 0; j < 4; ++j) bia[j] = bias[c0 + j];
#pragma unroll
  for (int j = 0; j < 4; ++j) bib[j] = (tl && c1 + j < DIM) ? bias[c1 + j] : 0.f;
  float s0[4] = {}, q0[4] = {}, s1[4] = {}, q1[4] = {};

  for (int g = 0; g < 8; ++g) {
    int nA = wv * 16 + g;      // local node ids within block
    int nB = nA + 8;
    int ebA = sptr[nA] - ebase, neA = sptr[nA + 1] - sptr[nA];
    int ebB = sptr[nB] - ebase, neB = sptr[nB + 1] - sptr[nB];
    int nemax = neA > neB ? neA : neB;
    const u16* xA = X + (size_t)(vb + nA) * DP;
    const u16* xB = X + (size_t)(vb + nB) * DP;
    uint2 mA = *(const uint2*)(xA + c0);
    uint2 mB = *(const uint2*)(xB + c0);
    uint2 tA, tB;
    if (tl) { tA = *(const uint2*)(xA + c1); tB = *(const uint2*)(xB + c1); }
    float A0[4] = {}, B0[4] = {}, A1[4] = {}, B1[4] = {};
    acc4(A0, mA); acc4(B0, mB);
    if (tl) { acc4(A1, tA); acc4(B1, tB); }

    for (int e = 0; e < nemax; e += 4) {
      bool aA = e < neA, aB = e < neB;   // padded degs are multiples of 4
      int oA = aA ? ebA + e : 0;
      int oB = aB ? ebB + e : 0;
      int ia[4], ib[4];
#pragma unroll
      for (int j = 0; j < 4; ++j) {
        int va = ip[oA + j], vbx = ip[oB + j];
        ia[j] = aA ? va : NN;
        ib[j] = aB ? vbx : NN;
      }
      const u16* pa[4]; const u16* pb[4];
#pragma unroll
      for (int j = 0; j < 4; ++j) {
        pa[j] = X + (size_t)ia[j] * DP;
        pb[j] = X + (size_t)ib[j] * DP;
      }
      uint2 ma[4], mb[4];
#pragma unroll
      for (int j = 0; j < 4; ++j) ma[j] = *(const uint2*)(pa[j] + c0);
#pragma unroll
      for (int j = 0; j < 4; ++j) mb[j] = *(const uint2*)(pb[j] + c0);
      uint2 ta[4], tb[4];
      if (tl) {
#pragma unroll
        for (int j = 0; j < 4; ++j) ta[j] = *(const uint2*)(pa[j] + c1);
#pragma unroll
        for (int j = 0; j < 4; ++j) tb[j] = *(const uint2*)(pb[j] + c1);
      }
#pragma unroll
      for (int j = 0; j < 4; ++j) { acc4(A0, ma[j]); acc4(B0, mb[j]); }
      if (tl) {
#pragma unroll
        for (int j = 0; j < 4; ++j) { acc4(A1, ta[j]); acc4(B1, tb[j]); }
      }
    }

    float dvA = dinv[vb + nA], dvB = dinv[vb + nB];
    u16* yA = Y + (size_t)(vb + nA) * DP;
    u16* yB = Y + (size_t)(vb + nB) * DP;
    float ya[4], yb[4];
#pragma unroll
    for (int j = 0; j < 4; ++j) {
      ya[j] = fmaf(dvA, A0[j], bia[j]);
      s0[j] += ya[j]; q0[j] += ya[j] * ya[j];
      yb[j] = fmaf(dvB, B0[j], bia[j]);
      s0[j] += yb[j]; q0[j] += yb[j] * yb[j];
    }
    uint2 wa, wb;
    wa.x = (unsigned)f2bf(ya[0]) | ((unsigned)f2bf(ya[1]) << 16);
    wa.y = (unsigned)f2bf(ya[2]) | ((unsigned)f2bf(ya[3]) << 16);
    wb.x = (unsigned)f2bf(yb[0]) | ((unsigned)f2bf(yb[1]) << 16);
    wb.y = (unsigned)f2bf(yb[2]) | ((unsigned)f2bf(yb[3]) << 16);
    *(uint2*)(yA + c0) = wa;
    *(uint2*)(yB + c0) = wb;
    if (tl) {
      float za[4], zb[4];
#pragma unroll
      for (int j = 0; j < 4; ++j) {
        za[j] = fmaf(dvA, A1[j], bib[j]);
        s1[j] += za[j]; q1[j] += za[j] * za[j];
        zb[j] = fmaf(dvB, B1[j], bib[j]);
        s1[j] += zb[j]; q1[j] += zb[j] * zb[j];
      }
      uint2 ua, ub;
      ua.x = (unsigned)f2bf(za[0]) | ((unsigned)f2bf(za[1]) << 16);
      ua.y = (unsigned)f2bf(za[2]) | ((unsigned)f2bf(za[3]) << 16);
      ub.x = (unsigned)f2bf(zb[0]) | ((unsigned)f2bf(zb[1]) << 16);
      ub.y = (unsigned)f2bf(zb[2]) | ((unsigned)f2bf(zb[3]) << 16);
      *(uint2*)(yA + c1) = ua;
      *(uint2*)(yB + c1) = ub;
    }
  }

#pragma unroll
  for (int j = 0; j < 4; ++j) { atomicAdd(&ls[c0 + j], s0[j]); atomicAdd(&lq[c0 + j], q0[j]); }
  if (tl) {
#pragma unroll
    for (int j = 0; j < 4; ++j) { atomicAdd(&ls[c1 + j], s1[j]); atomicAdd(&lq[c1 + j], q1[j]); }
  }
  __syncthreads();
  for (int i = tid; i < DP; i += 256) {
    atomicAdd(&bn_sum[i], ls[i]);
    atomicAdd(&bn_sq[i], lq[i]);
  }
}

__global__ void bn_finalize_kernel(const float* __restrict__ bn_sum, const float* __restrict__ bn_sq,
                                   const float* __restrict__ gamma, const float* __restrict__ beta,
                                   float* __restrict__ scale, float* __restrict__ shift) {
  int d = threadIdx.x;
  if (d >= DP) return;
  if (d < DIM) {
    const float invN = 1.0f / (float)NN;
    float mu = bn_sum[d] * invN;
    float var = bn_sq[d] * invN - mu * mu;
    float rstd = rsqrtf(var + BN_EPS);
    float sc = gamma[d] * rstd;
    scale[d] = sc;
    shift[d] = fmaf(-mu, sc, beta[d]);
  } else {
    scale[d] = 0.f;
    shift[d] = 0.f;
  }
}

// ---------------- MFMA Gram decode ----------------

__launch_bounds__(256)
__global__ void decode_kernel(const u16* __restrict__ H, float* __restrict__ out) {
  __shared__ __align__(16) u16 tile[4][2][NPG * BK];
  int tid = threadIdx.x, lane = tid & 63, wv = tid >> 6;
  int g = blockIdx.x * 4 + wv;
  const u16* Hg = H + (size_t)g * NPG * DP;
  const int ssl = lane & 3;
  int soff[4];
  const u16* sg[4];
#pragma unroll
  for (int i = 0; i < 4; ++i) {
    int r = (lane >> 2) + i * 16;
    soff[i] = r * BK + ((ssl ^ (r & 3) ^ ((r >> 2) & 3)) << 3);
    sg[i] = Hg + (size_t)r * DP + ssl * 8;
  }
  const int fr = lane & 15, fs = lane >> 4;
  const int fswz = ((fs ^ (fr & 3) ^ ((fr >> 2) & 3)) << 3);
  int foff[4];
#pragma unroll
  for (int i = 0; i < 4; ++i) foff[i] = (i * 16 + fr) * BK + fswz;

  u16* t0 = tile[wv][0];
  u16* t1 = tile[wv][1];
  uint4 rg[4];
#pragma unroll
  for (int i = 0; i < 4; ++i) rg[i] = *(const uint4*)(sg[i]);
#pragma unroll
  for (int i = 0; i < 4; ++i) *(uint4*)&t0[soff[i]] = rg[i];

  f32x4 acc[4][4];
#pragma unroll
  for (int i = 0; i < 4; ++i)
#pragma unroll
    for (int j = 0; j < 4; ++j) acc[i][j] = (f32x4){0.f, 0.f, 0.f, 0.f};

  for (int s = 0; s < DP / BK; ++s) {
    u16* cur = (s & 1) ? t1 : t0;
    u16* nxt = (s & 1) ? t0 : t1;
    const bool more = (s < DP / BK - 1);
    if (more) {
#pragma unroll
      for (int i = 0; i < 4; ++i) rg[i] = *(const uint4*)(sg[i] + (s + 1) * BK);
    }
    s16x8 af[4];
#pragma unroll
    for (int i = 0; i < 4; ++i) af[i] = *(const s16x8*)&cur[foff[i]];
#pragma unroll
    for (int i = 0; i < 4; ++i)
#pragma unroll
      for (int j = 0; j < 4; ++j)
        acc[i][j] = __builtin_amdgcn_mfma_f32_16x16x32_bf16(af[i], af[j], acc[i][j], 0, 0, 0);
    if (more) {
#pragma unroll
      for (int i = 0; i < 4; ++i) *(uint4*)&nxt[soff[i]] = rg[i];
    }
  }
  float* og = out + (size_t)g * NPG * NPG;
#pragma unroll
  for (int i = 0; i < 4; ++i) {
    int m0 = i * 16 + fs * 4;
#pragma unroll
    for (int j = 0; j < 4; ++j) {
      int n = j * 16 + fr;
#pragma unroll
      for (int r = 0; r < 4; ++r) og[(m0 + r) * NPG + n] = acc[i][j][r];
    }
  }
}

// ---------------- launch ----------------

extern "C" void kernel_launch(void* const* d_in, const int* in_sizes, int n_in,
                              void* d_out, int out_size, void* d_ws, size_t ws_size,
                              hipStream_t stream) {
  const int* xa = (const int*)d_in[0];
  const int* ei = (const int*)d_in[1];
  const float* emb = (const float*)d_in[2];
  const float* convW = (const float*)d_in[3];
  const float* convB = (const float*)d_in[4];
  const float* gamma = (const float*)d_in[5];
  const float* beta = (const float*)d_in[6];
  const float* postW = (const float*)d_in[7];
  const float* postB = (const float*)d_in[8];
  float* out = (float*)d_out;

  char* w = (char*)d_ws;
  u16* P = (u16*)w;          w += (size_t)(NN + 1) * DP * sizeof(u16);
  u16* Q = (u16*)w;          w += (size_t)(NN + 1) * DP * sizeof(u16);
  u16* Wp = (u16*)w;         w += (size_t)6 * 320 * DP * sizeof(u16);
  float* dinv = (float*)w;   w += (size_t)NN * sizeof(float);
  int* cnt = (int*)w;        w += (size_t)NN * sizeof(int);
  int* cnt_pad = (int*)w;    w += (size_t)NN * sizeof(int);
  int* indptr = (int*)w;     w += (size_t)(NN + 64) * sizeof(int);
  int* cursor = (int*)w;     w += (size_t)NN * sizeof(int);
  int* srcs = (int*)w;       w += (size_t)NEPAD * sizeof(int);
  int* partials = (int*)w;   w += 256 * sizeof(int);
  float* bn_sum = (float*)w; w += DP * sizeof(float);
  float* bn_sq = (float*)w;  w += DP * sizeof(float);
  float* bnscale = (float*)w; w += DP * sizeof(float);
  float* bnshift = (float*)w; w += DP * sizeof(float);

  size_t need = (size_t)(w - (char*)d_ws);
  if (ws_size < need) return;

  hipMemsetAsync(cnt, 0, (size_t)NN * sizeof(int), stream);
  hist_kernel<<<NE / 256, 256, 0, stream>>>(ei, cnt);
  pad_dinv_kernel<<<NN / 256, 256, 0, stream>>>(cnt, cnt_pad, dinv);
  scan_block_kernel<<<NN / 1024, 1024, 0, stream>>>(cnt_pad, indptr, partials);
  scan_partials_kernel<<<1, 128, 0, stream>>>(partials);
  add_offsets_kernel<<<NN / 256, 256, 0, stream>>>(indptr, partials, cursor, cnt_pad);
  fill_csr_kernel<<<NE / 256, 256, 0, stream>>>(ei, cursor, srcs);
  pad_fill_kernel<<<NN / 256, 256, 0, stream>>>(cursor, indptr, srcs);
  wpad_kernel<<<(6 * 320 * DP + 255) / 256, 256, 0, stream>>>(convW, postW, Wp);
  embed_kernel<<<NN, 128, 0, stream>>>(xa, emb, P);
  zrow_kernel<<<1, 288, 0, stream>>>(P, Q);

  for (int l = 0; l < NLAY; ++l) {
    gemm_kernel<<<NN / 128, 256, 0, stream>>>(
        P, Wp + (size_t)l * 320 * DP, Q,
        l ? bnscale : nullptr, l ? bnshift : nullptr, dinv, nullptr);
    hipMemsetAsync(bn_sum, 0, 2 * DP * sizeof(float), stream);
    spmm_kernel<<<NN / 64, 256, 0, stream>>>(Q, P, indptr, srcs, dinv,
                                             convB + (size_t)l * DIM, bn_sum, bn_sq);
    bn_finalize_kernel<<<1, DP, 0, stream>>>(bn_sum, bn_sq, gamma + (size_t)l * DIM,
                                             beta + (size_t)l * DIM, bnscale, bnshift);
  }

  gemm_kernel<<<NN / 128, 256, 0, stream>>>(
      P, Wp + (size_t)5 * 320 * DP, Q, bnscale, bnshift, nullptr, postB);

  decode_kernel<<<NGRAPH / 4, 256, 0, stream>>>(Q, out);
}

// Round 10
// 1029.826 us; speedup vs baseline: 3.2877x; 1.1814x over previous
//
#include <hip/hip_runtime.h>
#include <hip/hip_bf16.h>
#include <cstdint>

#define NN 131072      // nodes
#define NE 524288      // directed edges
#define DIM 275        // feature dim
#define DP 288         // padded stride (multiple of 16)
#define NFEAT 9
#define NVOC 128
#define NLAY 5
#define NPG 64
#define NGRAPH 2048
#define BN_EPS 1e-5f
#define BK 32
#define NEPAD (NE + 3 * NN)   // max padded edge count
#define LDSE 1536             // per-block staged edge indices (64 nodes)

typedef unsigned short u16;
typedef __attribute__((ext_vector_type(8))) short s16x8;
typedef __attribute__((ext_vector_type(4))) float f32x4;

__device__ __forceinline__ float bf2f(u16 u) {
  union { unsigned int i; float f; } x; x.i = ((unsigned int)u) << 16; return x.f;
}
__device__ __forceinline__ u16 f2bf(float f) {
  union { float f; unsigned int i; } x; x.f = f;
  unsigned int r = x.i + 0x7fffu + ((x.i >> 16) & 1u);
  return (u16)(r >> 16);
}
__device__ __forceinline__ void acc4(float* a, uint2 m) {
  a[0] += bf2f((u16)m.x); a[1] += bf2f((u16)(m.x >> 16));
  a[2] += bf2f((u16)m.y); a[3] += bf2f((u16)(m.y >> 16));
}

// ---------------- graph preprocessing ----------------

__global__ void hist_kernel(const int* __restrict__ ei, int* __restrict__ cnt) {
  int e = blockIdx.x * 256 + threadIdx.x;
  if (e < NE) atomicAdd(&cnt[ei[NE + e]], 1);
}

__global__ void pad_dinv_kernel(const int* __restrict__ cnt, int* __restrict__ cnt_pad,
                                float* __restrict__ dinv) {
  int v = blockIdx.x * 256 + threadIdx.x;
  if (v < NN) {
    int c = cnt[v];
    cnt_pad[v] = (c + 3) & ~3;
    dinv[v] = rsqrtf(1.0f + (float)c);
  }
}

__global__ void scan_block_kernel(const int* __restrict__ in, int* __restrict__ out_ex,
                                  int* __restrict__ partials) {
  __shared__ int buf[2][1024];
  int t = threadIdx.x;
  int idx = blockIdx.x * 1024 + t;
  int v = in[idx];
  buf[0][t] = v;
  __syncthreads();
  int cur = 0;
  for (int off = 1; off < 1024; off <<= 1) {
    int x = buf[cur][t];
    if (t >= off) x += buf[cur][t - off];
    buf[cur ^ 1][t] = x;
    __syncthreads();
    cur ^= 1;
  }
  out_ex[idx] = buf[cur][t] - v;
  if (t == 1023) partials[blockIdx.x] = buf[cur][t];
}

__global__ void scan_partials_kernel(int* partials) {
  __shared__ int buf[2][128];
  int t = threadIdx.x;
  int v = partials[t];
  buf[0][t] = v;
  __syncthreads();
  int cur = 0;
  for (int off = 1; off < 128; off <<= 1) {
    int x = buf[cur][t];
    if (t >= off) x += buf[cur][t - off];
    buf[cur ^ 1][t] = x;
    __syncthreads();
    cur ^= 1;
  }
  partials[t] = buf[cur][t] - v;
}

__global__ void add_offsets_kernel(int* __restrict__ indptr, const int* __restrict__ partials,
                                   int* __restrict__ cursor, const int* __restrict__ cnt_pad) {
  int i = blockIdx.x * 256 + threadIdx.x;
  if (i < NN) {
    int v = indptr[i] + partials[i >> 10];
    indptr[i] = v;
    cursor[i] = v;
    if (i == NN - 1) indptr[NN] = v + cnt_pad[NN - 1];
  }
}

__global__ void fill_csr_kernel(const int* __restrict__ ei, int* __restrict__ cursor,
                                int* __restrict__ srcs) {
  int e = blockIdx.x * 256 + threadIdx.x;
  if (e < NE) {
    int c = ei[NE + e];
    int p = atomicAdd(&cursor[c], 1);
    srcs[p] = ei[e];
  }
}

// pad slots point at the all-zeros row NN
__global__ void pad_fill_kernel(const int* __restrict__ cursor, const int* __restrict__ indptr,
                                int* __restrict__ srcs) {
  int v = blockIdx.x * 256 + threadIdx.x;
  if (v < NN) {
    int pe = indptr[v + 1];
    for (int p = cursor[v]; p < pe; ++p) srcs[p] = NN;
  }
}

__global__ void zrow_kernel(u16* __restrict__ P, u16* __restrict__ Q) {
  int i = threadIdx.x;
  if (i < DP) {
    P[(size_t)NN * DP + i] = 0;
    Q[(size_t)NN * DP + i] = 0;
  }
}

__global__ void wpad_kernel(const float* __restrict__ convW, const float* __restrict__ postW,
                            u16* __restrict__ Wp) {
  int i = blockIdx.x * 256 + threadIdx.x;
  const int total = 6 * 320 * DP;
  if (i >= total) return;
  int k = i % DP;
  int r = i / DP;
  int j = r % 320;
  int m = r / 320;
  float val = 0.f;
  if (j < DIM && k < DIM)
    val = (m < 5) ? convW[((size_t)m * DIM + j) * DIM + k] : postW[(size_t)j * DIM + k];
  Wp[i] = f2bf(val);
}

// ---------------- atom encoder ----------------

__global__ void embed_kernel(const int* __restrict__ xa, const float* __restrict__ emb,
                             u16* __restrict__ P) {
  int n = blockIdx.x;
  int idx[NFEAT];
#pragma unroll
  for (int f = 0; f < NFEAT; ++f) idx[f] = xa[n * NFEAT + f];
  for (int d = threadIdx.x; d < DP; d += 128) {
    float s = 0.f;
    if (d < DIM) {
#pragma unroll
      for (int f = 0; f < NFEAT; ++f) s += emb[((size_t)f * NVOC + idx[f]) * DIM + d];
    }
    P[(size_t)n * DP + d] = f2bf(s);
  }
}

// ---------------- MFMA GEMM v4: 64x288 single pass, BN-finalize fused ----------------
// C = rowscale .* (act(A) @ W^T) + colbias; act = relu(x*scale+shift), with
// scale/shift computed per-block from bn stats (fused bn_finalize). A staged
// once (transform once), 4KB LDS; B (L2-resident weights) restaged per block,
// 18KB. 4 waves 2Mx2N, wave = 32x144, acc 18 f32x4. 2 barriers/K-step.

__device__ __forceinline__ uint4 xform8s(uint4 r, const float* __restrict__ sc,
                                         const float* __restrict__ sh, int k) {
  union { uint4 u; u16 h[8]; } in, out;
  in.u = r;
#pragma unroll
  for (int j = 0; j < 8; ++j) {
    float x = fmaf(bf2f(in.h[j]), sc[k + j], sh[k + j]);
    out.h[j] = f2bf(fmaxf(x, 0.f));
  }
  return out.u;
}

__launch_bounds__(256)
__global__ void gemm_kernel(const u16* __restrict__ A, const u16* __restrict__ Wp,
                            u16* __restrict__ C,
                            const float* __restrict__ bn_sum, const float* __restrict__ bn_sq,
                            const float* __restrict__ gamma, const float* __restrict__ beta,
                            const float* __restrict__ rowscale, const float* __restrict__ colbias) {
  __shared__ __align__(16) u16 Asl[64 * BK];     // 4 KB
  __shared__ __align__(16) u16 Bsl[288 * BK];    // 18 KB
  __shared__ float scs[DP], shs[DP];
  const int tid = threadIdx.x, lane = tid & 63, wv = tid >> 6;
  const int wm = wv & 1, wn = wv >> 1;
  const int row0 = blockIdx.x * 64;
  const bool bn = (bn_sum != nullptr);

  // fused bn_finalize: per-block scale/shift table (stats are tiny + L2-hot)
  for (int d = tid; d < DP; d += 256) {
    float sc = 1.f, sh = 0.f;
    if (bn) {
      if (d < DIM) {
        const float invN = 1.0f / (float)NN;
        float mu = bn_sum[d] * invN;
        float var = bn_sq[d] * invN - mu * mu;
        float rstd = rsqrtf(var + BN_EPS);
        sc = gamma[d] * rstd;
        sh = fmaf(-mu, sc, beta[d]);
      } else {
        sc = 0.f; sh = 0.f;   // pad cols: relu(0*x+0)=0
      }
    }
    scs[d] = sc; shs[d] = sh;
  }

  // staging: thread t covers row t>>2, 16B chunk t&3 (XOR-swizzled)
  const int srow = tid >> 2, schk = tid & 3;
  const int swz = ((schk ^ (srow & 3) ^ ((srow >> 2) & 3)) << 3);
  const int awoff = srow * BK + swz;           // also B row srow+64i (same swz)
  const u16* ag = A + (size_t)(row0 + srow) * DP + schk * 8;
  const u16* bg = Wp + (size_t)srow * DP + schk * 8;
  const bool st4 = (tid < 128);                // B rows 256..287

  // fragment read offsets
  const int fr = lane & 15, fs = lane >> 4;
  int aoff[2], boff[9];
#pragma unroll
  for (int i = 0; i < 2; ++i) {
    int r = wm * 32 + i * 16 + fr;
    aoff[i] = r * BK + ((fs ^ (r & 3) ^ ((r >> 2) & 3)) << 3);
  }
#pragma unroll
  for (int j = 0; j < 9; ++j) {
    int r = wn * 144 + j * 16 + fr;
    boff[j] = r * BK + ((fs ^ (r & 3) ^ ((r >> 2) & 3)) << 3);
  }

  // prologue: load step-0 tiles (A from HBM, B from L2)
  uint4 ra = *(const uint4*)(ag);
  uint4 rb0 = *(const uint4*)(bg);
  uint4 rb1 = *(const uint4*)(bg + (size_t)64 * DP);
  uint4 rb2 = *(const uint4*)(bg + (size_t)128 * DP);
  uint4 rb3 = *(const uint4*)(bg + (size_t)192 * DP);
  uint4 rb4;
  if (st4) rb4 = *(const uint4*)(bg + (size_t)256 * DP);
  __syncthreads();                 // scs/shs ready
  if (bn) ra = xform8s(ra, scs, shs, schk * 8);
  *(uint4*)&Asl[awoff] = ra;
  *(uint4*)&Bsl[awoff] = rb0;
  *(uint4*)&Bsl[awoff + 64 * BK] = rb1;
  *(uint4*)&Bsl[awoff + 128 * BK] = rb2;
  *(uint4*)&Bsl[awoff + 192 * BK] = rb3;
  if (st4) *(uint4*)&Bsl[awoff + 256 * BK] = rb4;
  __syncthreads();

  f32x4 acc0[9], acc1[9];
#pragma unroll
  for (int j = 0; j < 9; ++j) {
    acc0[j] = (f32x4){0.f, 0.f, 0.f, 0.f};
    acc1[j] = (f32x4){0.f, 0.f, 0.f, 0.f};
  }

#pragma unroll 1
  for (int s = 0; s < 9; ++s) {
    const bool more = (s < 8);
    uint4 na, nb0, nb1, nb2, nb3, nb4;
    if (more) {   // issue next-step loads early; land during MFMA
      int k = (s + 1) * BK;
      na = *(const uint4*)(ag + k);
      nb0 = *(const uint4*)(bg + k);
      nb1 = *(const uint4*)(bg + (size_t)64 * DP + k);
      nb2 = *(const uint4*)(bg + (size_t)128 * DP + k);
      nb3 = *(const uint4*)(bg + (size_t)192 * DP + k);
      if (st4) nb4 = *(const uint4*)(bg + (size_t)256 * DP + k);
    }
    s16x8 af0 = *(const s16x8*)&Asl[aoff[0]];
    s16x8 af1 = *(const s16x8*)&Asl[aoff[1]];
#pragma unroll
    for (int j = 0; j < 9; ++j) {
      s16x8 bf = *(const s16x8*)&Bsl[boff[j]];
      acc0[j] = __builtin_amdgcn_mfma_f32_16x16x32_bf16(af0, bf, acc0[j], 0, 0, 0);
      acc1[j] = __builtin_amdgcn_mfma_f32_16x16x32_bf16(af1, bf, acc1[j], 0, 0, 0);
    }
    __syncthreads();   // all waves done reading LDS for step s
    if (more) {
      if (bn) na = xform8s(na, scs, shs, (s + 1) * BK + schk * 8);
      *(uint4*)&Asl[awoff] = na;
      *(uint4*)&Bsl[awoff] = nb0;
      *(uint4*)&Bsl[awoff + 64 * BK] = nb1;
      *(uint4*)&Bsl[awoff + 128 * BK] = nb2;
      *(uint4*)&Bsl[awoff + 192 * BK] = nb3;
      if (st4) *(uint4*)&Bsl[awoff + 256 * BK] = nb4;
      __syncthreads();
    }
  }

  // epilogue: D row = wm*32 + i*16 + fs*4 + r, col = wn*144 + j*16 + fr
#pragma unroll
  for (int i = 0; i < 2; ++i) {
    int gr0 = row0 + wm * 32 + i * 16 + fs * 4;
    float rs[4];
#pragma unroll
    for (int r = 0; r < 4; ++r) rs[r] = rowscale ? rowscale[gr0 + r] : 1.f;
#pragma unroll
    for (int j = 0; j < 9; ++j) {
      f32x4 av = i ? acc1[j] : acc0[j];
      int gc = wn * 144 + j * 16 + fr;
      float cb = (colbias && gc < DIM) ? colbias[gc] : 0.f;
#pragma unroll
      for (int r = 0; r < 4; ++r) {
        u16 o = (gc < DIM) ? f2bf(fmaf(av[r], rs[r], cb)) : (u16)0;
        C[(size_t)(gr0 + r) * DP + gc] = o;
      }
    }
  }
}

// ---------------- SpMM (r6 config, 103us): LDS idx + pair-interleave ----------------

__launch_bounds__(256)
__global__ void spmm_kernel(const u16* __restrict__ X, u16* __restrict__ Y,
                            const int* __restrict__ indptr, const int* __restrict__ srcs,
                            const float* __restrict__ dinv, const float* __restrict__ bias,
                            float* __restrict__ bn_sum, float* __restrict__ bn_sq) {
  __shared__ float ls[DP], lq[DP];
  __shared__ int sptr[65];
  __shared__ int sidx[LDSE];
  int tid = threadIdx.x;
  for (int i = tid; i < DP; i += 256) { ls[i] = 0.f; lq[i] = 0.f; }
  int vb = blockIdx.x * 64;
  if (tid < 65) sptr[tid] = indptr[vb + tid];
  __syncthreads();
  int ebase = sptr[0];
  int ecnt = sptr[64] - ebase;
  const int* ip;   // generic pointer: LDS fast path, global fallback
  if (ecnt <= LDSE) {
    for (int i = tid; i < ecnt; i += 256) sidx[i] = srcs[ebase + i];
    ip = sidx;
  } else {
    ip = srcs + ebase;
  }
  __syncthreads();

  int lane = tid & 63, wv = tid >> 6;
  int c0 = lane << 2;
  int c1 = 256 + (lane << 2);
  bool tl = lane < 8;
  float bia[4], bib[4];
#pragma unroll
  for (int j = 0; j < 4; ++j) bia[j] = bias[c0 + j];
#pragma unroll
  for (int j = 0; j < 4; ++j) bib[j] = (tl && c1 + j < DIM) ? bias[c1 + j] : 0.f;
  float s0[4] = {}, q0[4] = {}, s1[4] = {}, q1[4] = {};

  for (int g = 0; g < 8; ++g) {
    int nA = wv * 16 + g;      // local node ids within block
    int nB = nA + 8;
    int ebA = sptr[nA] - ebase, neA = sptr[nA + 1] - sptr[nA];
    int ebB = sptr[nB] - ebase, neB = sptr[nB + 1] - sptr[nB];
    int nemax = neA > neB ? neA : neB;
    const u16* xA = X + (size_t)(vb + nA) * DP;
    const u16* xB = X + (size_t)(vb + nB) * DP;
    uint2 mA = *(const uint2*)(xA + c0);
    uint2 mB = *(const uint2*)(xB + c0);
    uint2 tA, tB;
    if (tl) { tA = *(const uint2*)(xA + c1); tB = *(const uint2*)(xB + c1); }
    float A0[4] = {}, B0[4] = {}, A1[4] = {}, B1[4] = {};
    acc4(A0, mA); acc4(B0, mB);
    if (tl) { acc4(A1, tA); acc4(B1, tB); }

    for (int e = 0; e < nemax; e += 4) {
      bool aA = e < neA, aB = e < neB;   // padded degs are multiples of 4
      int oA = aA ? ebA + e : 0;
      int oB = aB ? ebB + e : 0;
      int ia[4], ib[4];
#pragma unroll
      for (int j = 0; j < 4; ++j) {
        int va = ip[oA + j], vbx = ip[oB + j];
        ia[j] = aA ? va : NN;
        ib[j] = aB ? vbx : NN;
      }
      const u16* pa[4]; const u16* pb[4];
#pragma unroll
      for (int j = 0; j < 4; ++j) {
        pa[j] = X + (size_t)ia[j] * DP;
        pb[j] = X + (size_t)ib[j] * DP;
      }
      uint2 ma[4], mb[4];
#pragma unroll
      for (int j = 0; j < 4; ++j) ma[j] = *(const uint2*)(pa[j] + c0);
#pragma unroll
      for (int j = 0; j < 4; ++j) mb[j] = *(const uint2*)(pb[j] + c0);
      uint2 ta[4], tb[4];
      if (tl) {
#pragma unroll
        for (int j = 0; j < 4; ++j) ta[j] = *(const uint2*)(pa[j] + c1);
#pragma unroll
        for (int j = 0; j < 4; ++j) tb[j] = *(const uint2*)(pb[j] + c1);
      }
#pragma unroll
      for (int j = 0; j < 4; ++j) { acc4(A0, ma[j]); acc4(B0, mb[j]); }
      if (tl) {
#pragma unroll
        for (int j = 0; j < 4; ++j) { acc4(A1, ta[j]); acc4(B1, tb[j]); }
      }
    }

    float dvA = dinv[vb + nA], dvB = dinv[vb + nB];
    u16* yA = Y + (size_t)(vb + nA) * DP;
    u16* yB = Y + (size_t)(vb + nB) * DP;
    float ya[4], yb[4];
#pragma unroll
    for (int j = 0; j < 4; ++j) {
      ya[j] = fmaf(dvA, A0[j], bia[j]);
      s0[j] += ya[j]; q0[j] += ya[j] * ya[j];
      yb[j] = fmaf(dvB, B0[j], bia[j]);
      s0[j] += yb[j]; q0[j] += yb[j] * yb[j];
    }
    uint2 wa, wb;
    wa.x = (unsigned)f2bf(ya[0]) | ((unsigned)f2bf(ya[1]) << 16);
    wa.y = (unsigned)f2bf(ya[2]) | ((unsigned)f2bf(ya[3]) << 16);
    wb.x = (unsigned)f2bf(yb[0]) | ((unsigned)f2bf(yb[1]) << 16);
    wb.y = (unsigned)f2bf(yb[2]) | ((unsigned)f2bf(yb[3]) << 16);
    *(uint2*)(yA + c0) = wa;
    *(uint2*)(yB + c0) = wb;
    if (tl) {
      float za[4], zb[4];
#pragma unroll
      for (int j = 0; j < 4; ++j) {
        za[j] = fmaf(dvA, A1[j], bib[j]);
        s1[j] += za[j]; q1[j] += za[j] * za[j];
        zb[j] = fmaf(dvB, B1[j], bib[j]);
        s1[j] += zb[j]; q1[j] += zb[j] * zb[j];
      }
      uint2 ua, ub;
      ua.x = (unsigned)f2bf(za[0]) | ((unsigned)f2bf(za[1]) << 16);
      ua.y = (unsigned)f2bf(za[2]) | ((unsigned)f2bf(za[3]) << 16);
      ub.x = (unsigned)f2bf(zb[0]) | ((unsigned)f2bf(zb[1]) << 16);
      ub.y = (unsigned)f2bf(zb[2]) | ((unsigned)f2bf(zb[3]) << 16);
      *(uint2*)(yA + c1) = ua;
      *(uint2*)(yB + c1) = ub;
    }
  }

#pragma unroll
  for (int j = 0; j < 4; ++j) { atomicAdd(&ls[c0 + j], s0[j]); atomicAdd(&lq[c0 + j], q0[j]); }
  if (tl) {
#pragma unroll
    for (int j = 0; j < 4; ++j) { atomicAdd(&ls[c1 + j], s1[j]); atomicAdd(&lq[c1 + j], q1[j]); }
  }
  __syncthreads();
  for (int i = tid; i < DP; i += 256) {
    atomicAdd(&bn_sum[i], ls[i]);
    atomicAdd(&bn_sq[i], lq[i]);
  }
}

// ---------------- MFMA Gram decode ----------------

__launch_bounds__(256)
__global__ void decode_kernel(const u16* __restrict__ H, float* __restrict__ out) {
  __shared__ __align__(16) u16 tile[4][2][NPG * BK];
  int tid = threadIdx.x, lane = tid & 63, wv = tid >> 6;
  int g = blockIdx.x * 4 + wv;
  const u16* Hg = H + (size_t)g * NPG * DP;
  const int ssl = lane & 3;
  int soff[4];
  const u16* sg[4];
#pragma unroll
  for (int i = 0; i < 4; ++i) {
    int r = (lane >> 2) + i * 16;
    soff[i] = r * BK + ((ssl ^ (r & 3) ^ ((r >> 2) & 3)) << 3);
    sg[i] = Hg + (size_t)r * DP + ssl * 8;
  }
  const int fr = lane & 15, fs = lane >> 4;
  const int fswz = ((fs ^ (fr & 3) ^ ((fr >> 2) & 3)) << 3);
  int foff[4];
#pragma unroll
  for (int i = 0; i < 4; ++i) foff[i] = (i * 16 + fr) * BK + fswz;

  u16* t0 = tile[wv][0];
  u16* t1 = tile[wv][1];
  uint4 rg[4];
#pragma unroll
  for (int i = 0; i < 4; ++i) rg[i] = *(const uint4*)(sg[i]);
#pragma unroll
  for (int i = 0; i < 4; ++i) *(uint4*)&t0[soff[i]] = rg[i];

  f32x4 acc[4][4];
#pragma unroll
  for (int i = 0; i < 4; ++i)
#pragma unroll
    for (int j = 0; j < 4; ++j) acc[i][j] = (f32x4){0.f, 0.f, 0.f, 0.f};

  for (int s = 0; s < DP / BK; ++s) {
    u16* cur = (s & 1) ? t1 : t0;
    u16* nxt = (s & 1) ? t0 : t1;
    const bool more = (s < DP / BK - 1);
    if (more) {
#pragma unroll
      for (int i = 0; i < 4; ++i) rg[i] = *(const uint4*)(sg[i] + (s + 1) * BK);
    }
    s16x8 af[4];
#pragma unroll
    for (int i = 0; i < 4; ++i) af[i] = *(const s16x8*)&cur[foff[i]];
#pragma unroll
    for (int i = 0; i < 4; ++i)
#pragma unroll
      for (int j = 0; j < 4; ++j)
        acc[i][j] = __builtin_amdgcn_mfma_f32_16x16x32_bf16(af[i], af[j], acc[i][j], 0, 0, 0);
    if (more) {
#pragma unroll
      for (int i = 0; i < 4; ++i) *(uint4*)&nxt[soff[i]] = rg[i];
    }
  }
  float* og = out + (size_t)g * NPG * NPG;
#pragma unroll
  for (int i = 0; i < 4; ++i) {
    int m0 = i * 16 + fs * 4;
#pragma unroll
    for (int j = 0; j < 4; ++j) {
      int n = j * 16 + fr;
#pragma unroll
      for (int r = 0; r < 4; ++r) og[(m0 + r) * NPG + n] = acc[i][j][r];
    }
  }
}

// ---------------- launch ----------------

extern "C" void kernel_launch(void* const* d_in, const int* in_sizes, int n_in,
                              void* d_out, int out_size, void* d_ws, size_t ws_size,
                              hipStream_t stream) {
  const int* xa = (const int*)d_in[0];
  const int* ei = (const int*)d_in[1];
  const float* emb = (const float*)d_in[2];
  const float* convW = (const float*)d_in[3];
  const float* convB = (const float*)d_in[4];
  const float* gamma = (const float*)d_in[5];
  const float* beta = (const float*)d_in[6];
  const float* postW = (const float*)d_in[7];
  const float* postB = (const float*)d_in[8];
  float* out = (float*)d_out;

  char* w = (char*)d_ws;
  u16* P = (u16*)w;          w += (size_t)(NN + 1) * DP * sizeof(u16);
  u16* Q = (u16*)w;          w += (size_t)(NN + 1) * DP * sizeof(u16);
  u16* Wp = (u16*)w;         w += (size_t)6 * 320 * DP * sizeof(u16);
  float* dinv = (float*)w;   w += (size_t)NN * sizeof(float);
  int* cnt = (int*)w;        w += (size_t)NN * sizeof(int);
  int* cnt_pad = (int*)w;    w += (size_t)NN * sizeof(int);
  int* indptr = (int*)w;     w += (size_t)(NN + 64) * sizeof(int);
  int* cursor = (int*)w;     w += (size_t)NN * sizeof(int);
  int* srcs = (int*)w;       w += (size_t)NEPAD * sizeof(int);
  int* partials = (int*)w;   w += 256 * sizeof(int);
  float* bnstats = (float*)w; w += (size_t)NLAY * 2 * DP * sizeof(float);

  size_t need = (size_t)(w - (char*)d_ws);
  if (ws_size < need) return;

  hipMemsetAsync(cnt, 0, (size_t)NN * sizeof(int), stream);
  hipMemsetAsync(bnstats, 0, (size_t)NLAY * 2 * DP * sizeof(float), stream);
  hist_kernel<<<NE / 256, 256, 0, stream>>>(ei, cnt);
  pad_dinv_kernel<<<NN / 256, 256, 0, stream>>>(cnt, cnt_pad, dinv);
  scan_block_kernel<<<NN / 1024, 1024, 0, stream>>>(cnt_pad, indptr, partials);
  scan_partials_kernel<<<1, 128, 0, stream>>>(partials);
  add_offsets_kernel<<<NN / 256, 256, 0, stream>>>(indptr, partials, cursor, cnt_pad);
  fill_csr_kernel<<<NE / 256, 256, 0, stream>>>(ei, cursor, srcs);
  pad_fill_kernel<<<NN / 256, 256, 0, stream>>>(cursor, indptr, srcs);
  wpad_kernel<<<(6 * 320 * DP + 255) / 256, 256, 0, stream>>>(convW, postW, Wp);
  embed_kernel<<<NN, 128, 0, stream>>>(xa, emb, P);
  zrow_kernel<<<1, 288, 0, stream>>>(P, Q);

  for (int l = 0; l < NLAY; ++l) {
    const float* bs = l ? bnstats + (size_t)(l - 1) * 2 * DP : nullptr;
    gemm_kernel<<<NN / 64, 256, 0, stream>>>(
        P, Wp + (size_t)l * 320 * DP, Q,
        bs, bs ? bs + DP : nullptr,
        l ? gamma + (size_t)(l - 1) * DIM : nullptr,
        l ? beta + (size_t)(l - 1) * DIM : nullptr,
        dinv, nullptr);
    spmm_kernel<<<NN / 64, 256, 0, stream>>>(Q, P, indptr, srcs, dinv,
                                             convB + (size_t)l * DIM,
                                             bnstats + (size_t)l * 2 * DP,
                                             bnstats + (size_t)l * 2 * DP + DP);
  }

  const float* bs5 = bnstats + (size_t)4 * 2 * DP;
  gemm_kernel<<<NN / 64, 256, 0, stream>>>(
      P, Wp + (size_t)5 * 320 * DP, Q, bs5, bs5 + DP,
      gamma + (size_t)4 * DIM, beta + (size_t)4 * DIM, nullptr, postB);

  decode_kernel<<<NGRAPH / 4, 256, 0, stream>>>(Q, out);
}

// Round 11
// 996.616 us; speedup vs baseline: 3.3973x; 1.0333x over previous
//
#include <hip/hip_runtime.h>
#include <hip/hip_bf16.h>
#include <cstdint>

#define NN 131072      // nodes
#define NE 524288      // directed edges
#define DIM 275        // feature dim
#define DP 288         // padded stride (multiple of 16)
#define NFEAT 9
#define NVOC 128
#define NLAY 5
#define NPG 64
#define NGRAPH 2048
#define BN_EPS 1e-5f
#define BK 32
#define NEPAD (NE + 3 * NN)   // max padded edge count
#define LDSE 1536             // per-block staged edge indices (64 nodes)

typedef unsigned short u16;
typedef __attribute__((ext_vector_type(8))) short s16x8;
typedef __attribute__((ext_vector_type(4))) float f32x4;

// global_load_lds: linear LDS dest (wave base + lane*16), per-lane global src
#define GLL16(g, l) __builtin_amdgcn_global_load_lds( \
    (const __attribute__((address_space(1))) unsigned int*)(g), \
    (__attribute__((address_space(3))) unsigned int*)(l), 16, 0, 0)

__device__ __forceinline__ float bf2f(u16 u) {
  union { unsigned int i; float f; } x; x.i = ((unsigned int)u) << 16; return x.f;
}
__device__ __forceinline__ u16 f2bf(float f) {
  union { float f; unsigned int i; } x; x.f = f;
  unsigned int r = x.i + 0x7fffu + ((x.i >> 16) & 1u);
  return (u16)(r >> 16);
}
__device__ __forceinline__ void acc4(float* a, uint2 m) {
  a[0] += bf2f((u16)m.x); a[1] += bf2f((u16)(m.x >> 16));
  a[2] += bf2f((u16)m.y); a[3] += bf2f((u16)(m.y >> 16));
}

// ---------------- graph preprocessing ----------------

__global__ void hist_kernel(const int* __restrict__ ei, int* __restrict__ cnt) {
  int e = blockIdx.x * 256 + threadIdx.x;
  if (e < NE) atomicAdd(&cnt[ei[NE + e]], 1);
}

__global__ void pad_dinv_kernel(const int* __restrict__ cnt, int* __restrict__ cnt_pad,
                                float* __restrict__ dinv) {
  int v = blockIdx.x * 256 + threadIdx.x;
  if (v < NN) {
    int c = cnt[v];
    cnt_pad[v] = (c + 3) & ~3;
    dinv[v] = rsqrtf(1.0f + (float)c);
  }
}

__global__ void scan_block_kernel(const int* __restrict__ in, int* __restrict__ out_ex,
                                  int* __restrict__ partials) {
  __shared__ int buf[2][1024];
  int t = threadIdx.x;
  int idx = blockIdx.x * 1024 + t;
  int v = in[idx];
  buf[0][t] = v;
  __syncthreads();
  int cur = 0;
  for (int off = 1; off < 1024; off <<= 1) {
    int x = buf[cur][t];
    if (t >= off) x += buf[cur][t - off];
    buf[cur ^ 1][t] = x;
    __syncthreads();
    cur ^= 1;
  }
  out_ex[idx] = buf[cur][t] - v;
  if (t == 1023) partials[blockIdx.x] = buf[cur][t];
}

__global__ void scan_partials_kernel(int* partials) {
  __shared__ int buf[2][128];
  int t = threadIdx.x;
  int v = partials[t];
  buf[0][t] = v;
  __syncthreads();
  int cur = 0;
  for (int off = 1; off < 128; off <<= 1) {
    int x = buf[cur][t];
    if (t >= off) x += buf[cur][t - off];
    buf[cur ^ 1][t] = x;
    __syncthreads();
    cur ^= 1;
  }
  partials[t] = buf[cur][t] - v;
}

__global__ void add_offsets_kernel(int* __restrict__ indptr, const int* __restrict__ partials,
                                   int* __restrict__ cursor, const int* __restrict__ cnt_pad) {
  int i = blockIdx.x * 256 + threadIdx.x;
  if (i < NN) {
    int v = indptr[i] + partials[i >> 10];
    indptr[i] = v;
    cursor[i] = v;
    if (i == NN - 1) indptr[NN] = v + cnt_pad[NN - 1];
  }
}

__global__ void fill_csr_kernel(const int* __restrict__ ei, int* __restrict__ cursor,
                                int* __restrict__ srcs) {
  int e = blockIdx.x * 256 + threadIdx.x;
  if (e < NE) {
    int c = ei[NE + e];
    int p = atomicAdd(&cursor[c], 1);
    srcs[p] = ei[e];
  }
}

// pad slots point at the all-zeros row NN
__global__ void pad_fill_kernel(const int* __restrict__ cursor, const int* __restrict__ indptr,
                                int* __restrict__ srcs) {
  int v = blockIdx.x * 256 + threadIdx.x;
  if (v < NN) {
    int pe = indptr[v + 1];
    for (int p = cursor[v]; p < pe; ++p) srcs[p] = NN;
  }
}

__global__ void zrow_kernel(u16* __restrict__ P, u16* __restrict__ Q) {
  int i = threadIdx.x;
  if (i < DP) {
    P[(size_t)NN * DP + i] = 0;
    Q[(size_t)NN * DP + i] = 0;
  }
}

// Pad + PRE-SWIZZLE weights: within each 64B (32-elem) K-group of row j, the
// four 16B chunks are stored at pos p = chunk ^ s(j), s(j)=(j&3)^((j>>2)&3).
// gemm stages them to LDS linearly (global_load_lds) and reads with the same
// XOR -> conflict-free, both-sides-consistent (rule #21).
__global__ void wpad_kernel(const float* __restrict__ convW, const float* __restrict__ postW,
                            u16* __restrict__ Wp) {
  int i = blockIdx.x * 256 + threadIdx.x;
  const int total = 6 * 320 * DP;
  if (i >= total) return;
  int k = i % DP;
  int r = i / DP;
  int j = r % 320;
  int m = r / 320;
  float val = 0.f;
  if (j < DIM && k < DIM)
    val = (m < 5) ? convW[((size_t)m * DIM + j) * DIM + k] : postW[(size_t)j * DIM + k];
  int s = (j & 3) ^ ((j >> 2) & 3);
  int kout = (k & ~24) | (((((k >> 3) & 3)) ^ s) << 3);
  Wp[(size_t)r * DP + kout] = f2bf(val);
}

// ---------------- atom encoder ----------------

__global__ void embed_kernel(const int* __restrict__ xa, const float* __restrict__ emb,
                             u16* __restrict__ P) {
  int n = blockIdx.x;
  int idx[NFEAT];
#pragma unroll
  for (int f = 0; f < NFEAT; ++f) idx[f] = xa[n * NFEAT + f];
  for (int d = threadIdx.x; d < DP; d += 128) {
    float s = 0.f;
    if (d < DIM) {
#pragma unroll
      for (int f = 0; f < NFEAT; ++f) s += emb[((size_t)f * NVOC + idx[f]) * DIM + d];
    }
    P[(size_t)n * DP + d] = f2bf(s);
  }
}

// ---------------- MFMA GEMM v5: dbuf + global_load_lds B, 1 barrier/step ----------------
// Block = 64 rows x 288 cols, 4 waves 2Mx2N, wave 32x144, acc 18 f32x4.
// B staged from pre-swizzled Wp via global_load_lds (18 wave-instrs per step,
// 1KB each); A reg-staged (BN+ReLU transform in-register), ds_write swizzled.
// Double-buffered LDS -> single barrier per K-step (prefetch lands under MFMA).

__device__ __forceinline__ uint4 xform8s(uint4 r, const float* __restrict__ sc,
                                         const float* __restrict__ sh, int k) {
  union { uint4 u; u16 h[8]; } in, out;
  in.u = r;
#pragma unroll
  for (int j = 0; j < 8; ++j) {
    float x = fmaf(bf2f(in.h[j]), sc[k + j], sh[k + j]);
    out.h[j] = f2bf(fmaxf(x, 0.f));
  }
  return out.u;
}

__launch_bounds__(256)
__global__ void gemm_kernel(const u16* __restrict__ A, const u16* __restrict__ Wq,
                            u16* __restrict__ C,
                            const float* __restrict__ bn_sum, const float* __restrict__ bn_sq,
                            const float* __restrict__ gamma, const float* __restrict__ beta,
                            const float* __restrict__ rowscale, const float* __restrict__ colbias) {
  __shared__ __align__(16) u16 Asl[2][64 * BK];     // 2 x 4 KB
  __shared__ __align__(16) u16 Bsl[2][288 * BK];    // 2 x 18 KB
  __shared__ float scs[DP], shs[DP];
  const int tid = threadIdx.x, lane = tid & 63, wv = tid >> 6;
  const int wm = wv & 1, wn = wv >> 1;
  const int row0 = blockIdx.x * 64;
  const bool bn = (bn_sum != nullptr);

  // fused bn_finalize
  for (int d = tid; d < DP; d += 256) {
    float sc = 1.f, sh = 0.f;
    if (bn) {
      if (d < DIM) {
        const float invN = 1.0f / (float)NN;
        float mu = bn_sum[d] * invN;
        float var = bn_sq[d] * invN - mu * mu;
        float rstd = rsqrtf(var + BN_EPS);
        sc = gamma[d] * rstd;
        sh = fmaf(-mu, sc, beta[d]);
      } else {
        sc = 0.f; sh = 0.f;
      }
    }
    scs[d] = sc; shs[d] = sh;
  }

  // A staging: thread t covers row t>>2, 16B chunk t&3 (XOR-swizzled write)
  const int srow = tid >> 2, schk = tid & 3;
  const int swz = ((schk ^ (srow & 3) ^ ((srow >> 2) & 3)) << 3);
  const int awoff = srow * BK + swz;
  const u16* ag = A + (size_t)(row0 + srow) * DP + schk * 8;
  // B staging (gll): instr i covers rows i*16..i*16+15; lane l -> row i*16+(l>>2), pos l&3
  const int grow = lane >> 2, gchk = (lane & 3) * 8;

  // fragment read offsets
  const int fr = lane & 15, fs = lane >> 4;
  int aoff[2], boff[9];
#pragma unroll
  for (int i = 0; i < 2; ++i) {
    int r = wm * 32 + i * 16 + fr;
    aoff[i] = r * BK + ((fs ^ (r & 3) ^ ((r >> 2) & 3)) << 3);
  }
#pragma unroll
  for (int j = 0; j < 9; ++j) {
    int r = wn * 144 + j * 16 + fr;
    boff[j] = r * BK + ((fs ^ (r & 3) ^ ((r >> 2) & 3)) << 3);
  }

  // prologue: issue B0 gll, load A0, finalize scs
  for (int i = wv; i < 18; i += 4)
    GLL16(Wq + (size_t)(i * 16 + grow) * DP + gchk, &Bsl[0][i * 512]);
  uint4 ra = *(const uint4*)(ag);
  __syncthreads();               // scs/shs ready; B0 gll drained by waitcnt
  if (bn) ra = xform8s(ra, scs, shs, schk * 8);
  *(uint4*)&Asl[0][awoff] = ra;
  __syncthreads();

  f32x4 acc0[9], acc1[9];
#pragma unroll
  for (int j = 0; j < 9; ++j) {
    acc0[j] = (f32x4){0.f, 0.f, 0.f, 0.f};
    acc1[j] = (f32x4){0.f, 0.f, 0.f, 0.f};
  }

#pragma unroll 1
  for (int s = 0; s < 9; ++s) {
    const int cur = s & 1;
    const bool more = (s < 8);
    uint4 na;
    if (more) {   // prefetch s+1 into other buffer; lands under MFMA
      int k = (s + 1) * BK;
      for (int i = wv; i < 18; i += 4)
        GLL16(Wq + (size_t)(i * 16 + grow) * DP + k + gchk, &Bsl[cur ^ 1][i * 512]);
      na = *(const uint4*)(ag + k);
    }
    s16x8 af0 = *(const s16x8*)&Asl[cur][aoff[0]];
    s16x8 af1 = *(const s16x8*)&Asl[cur][aoff[1]];
#pragma unroll
    for (int j = 0; j < 9; ++j) {
      s16x8 bf = *(const s16x8*)&Bsl[cur][boff[j]];
      acc0[j] = __builtin_amdgcn_mfma_f32_16x16x32_bf16(af0, bf, acc0[j], 0, 0, 0);
      acc1[j] = __builtin_amdgcn_mfma_f32_16x16x32_bf16(af1, bf, acc1[j], 0, 0, 0);
    }
    if (more) {
      if (bn) na = xform8s(na, scs, shs, (s + 1) * BK + schk * 8);
      *(uint4*)&Asl[cur ^ 1][awoff] = na;
    }
    __syncthreads();   // one barrier/step: drains gll + ds_write, releases cur
  }

  // epilogue: D row = wm*32 + i*16 + fs*4 + r, col = wn*144 + j*16 + fr
#pragma unroll
  for (int i = 0; i < 2; ++i) {
    int gr0 = row0 + wm * 32 + i * 16 + fs * 4;
    float rs[4];
#pragma unroll
    for (int r = 0; r < 4; ++r) rs[r] = rowscale ? rowscale[gr0 + r] : 1.f;
#pragma unroll
    for (int j = 0; j < 9; ++j) {
      f32x4 av = i ? acc1[j] : acc0[j];
      int gc = wn * 144 + j * 16 + fr;
      float cb = (colbias && gc < DIM) ? colbias[gc] : 0.f;
#pragma unroll
      for (int r = 0; r < 4; ++r) {
        u16 o = (gc < DIM) ? f2bf(fmaf(av[r], rs[r], cb)) : (u16)0;
        C[(size_t)(gr0 + r) * DP + gc] = o;
      }
    }
  }
}

// ---------------- SpMM v6: pair-interleave, c1 merged across pair ----------------
// Per 4-edge batch: 2 int4 idx loads + 8 c0 gathers + 4 c1 gathers (lanes 0-15
// cover both nodes' tail cols) = 14 load-issues vs v5's 24, same bytes.

__launch_bounds__(256)
__global__ void spmm_kernel(const u16* __restrict__ X, u16* __restrict__ Y,
                            const int* __restrict__ indptr, const int* __restrict__ srcs,
                            const float* __restrict__ dinv, const float* __restrict__ bias,
                            float* __restrict__ bn_sum, float* __restrict__ bn_sq) {
  __shared__ float ls[DP], lq[DP];
  __shared__ int sptr[65];
  __shared__ __align__(16) int sidx[LDSE];
  int tid = threadIdx.x;
  for (int i = tid; i < DP; i += 256) { ls[i] = 0.f; lq[i] = 0.f; }
  int vb = blockIdx.x * 64;
  if (tid < 65) sptr[tid] = indptr[vb + tid];
  __syncthreads();
  int ebase = sptr[0];
  int ecnt = sptr[64] - ebase;
  const int* ip;
  if (ecnt <= LDSE) {
    for (int i = tid; i < ecnt; i += 256) sidx[i] = srcs[ebase + i];
    ip = sidx;
  } else {
    ip = srcs + ebase;
  }
  __syncthreads();

  int lane = tid & 63, wv = tid >> 6;
  int c0 = lane << 2;
  int lane2 = lane & 7;
  int c1 = 256 + (lane2 << 2);
  bool tl = lane < 16;          // lanes 0-7: node A tail; 8-15: node B tail
  bool loA = lane < 8;
  float bia[4], bib[4];
#pragma unroll
  for (int j = 0; j < 4; ++j) bia[j] = bias[c0 + j];
#pragma unroll
  for (int j = 0; j < 4; ++j) bib[j] = (tl && c1 + j < DIM) ? bias[c1 + j] : 0.f;
  float s0[4] = {}, q0[4] = {}, s1[4] = {}, q1[4] = {};

  for (int g = 0; g < 8; ++g) {
    int nA = wv * 16 + g;
    int nB = nA + 8;
    int ebA = sptr[nA] - ebase, neA = sptr[nA + 1] - sptr[nA];
    int ebB = sptr[nB] - ebase, neB = sptr[nB + 1] - sptr[nB];
    int nemax = neA > neB ? neA : neB;
    const u16* xA = X + (size_t)(vb + nA) * DP;
    const u16* xB = X + (size_t)(vb + nB) * DP;
    uint2 mA = *(const uint2*)(xA + c0);
    uint2 mB = *(const uint2*)(xB + c0);
    uint2 tS;
    if (tl) tS = *(const uint2*)((loA ? xA : xB) + c1);
    float A0[4] = {}, B0[4] = {}, C1[4] = {};
    acc4(A0, mA); acc4(B0, mB);
    if (tl) acc4(C1, tS);

    for (int e = 0; e < nemax; e += 4) {
      bool aA = e < neA, aB = e < neB;   // padded degs are multiples of 4
      int oA = aA ? ebA + e : 0;
      int oB = aB ? ebB + e : 0;
      int4 i4a = *(const int4*)(ip + oA);
      int4 i4b = *(const int4*)(ip + oB);
      int ia[4], ib[4];
      ia[0] = aA ? i4a.x : NN; ia[1] = aA ? i4a.y : NN;
      ia[2] = aA ? i4a.z : NN; ia[3] = aA ? i4a.w : NN;
      ib[0] = aB ? i4b.x : NN; ib[1] = aB ? i4b.y : NN;
      ib[2] = aB ? i4b.z : NN; ib[3] = aB ? i4b.w : NN;
      const u16* pa[4]; const u16* pb[4];
#pragma unroll
      for (int j = 0; j < 4; ++j) {
        pa[j] = X + (size_t)ia[j] * DP;
        pb[j] = X + (size_t)ib[j] * DP;
      }
      uint2 ma[4], mb[4];
#pragma unroll
      for (int j = 0; j < 4; ++j) ma[j] = *(const uint2*)(pa[j] + c0);
#pragma unroll
      for (int j = 0; j < 4; ++j) mb[j] = *(const uint2*)(pb[j] + c0);
      uint2 tc[4];
      if (tl) {
#pragma unroll
        for (int j = 0; j < 4; ++j) tc[j] = *(const uint2*)((loA ? pa[j] : pb[j]) + c1);
      }
#pragma unroll
      for (int j = 0; j < 4; ++j) { acc4(A0, ma[j]); acc4(B0, mb[j]); }
      if (tl) {
#pragma unroll
        for (int j = 0; j < 4; ++j) acc4(C1, tc[j]);
      }
    }

    float dvA = dinv[vb + nA], dvB = dinv[vb + nB];
    u16* yA = Y + (size_t)(vb + nA) * DP;
    u16* yB = Y + (size_t)(vb + nB) * DP;
    float ya[4], yb[4];
#pragma unroll
    for (int j = 0; j < 4; ++j) {
      ya[j] = fmaf(dvA, A0[j], bia[j]);
      s0[j] += ya[j]; q0[j] += ya[j] * ya[j];
      yb[j] = fmaf(dvB, B0[j], bia[j]);
      s0[j] += yb[j]; q0[j] += yb[j] * yb[j];
    }
    uint2 wa, wb;
    wa.x = (unsigned)f2bf(ya[0]) | ((unsigned)f2bf(ya[1]) << 16);
    wa.y = (unsigned)f2bf(ya[2]) | ((unsigned)f2bf(ya[3]) << 16);
    wb.x = (unsigned)f2bf(yb[0]) | ((unsigned)f2bf(yb[1]) << 16);
    wb.y = (unsigned)f2bf(yb[2]) | ((unsigned)f2bf(yb[3]) << 16);
    *(uint2*)(yA + c0) = wa;
    *(uint2*)(yB + c0) = wb;
    if (tl) {
      float dvS = loA ? dvA : dvB;
      u16* yS = loA ? yA : yB;
      float z[4];
#pragma unroll
      for (int j = 0; j < 4; ++j) {
        z[j] = fmaf(dvS, C1[j], bib[j]);
        s1[j] += z[j]; q1[j] += z[j] * z[j];
      }
      uint2 w2;
      w2.x = (unsigned)f2bf(z[0]) | ((unsigned)f2bf(z[1]) << 16);
      w2.y = (unsigned)f2bf(z[2]) | ((unsigned)f2bf(z[3]) << 16);
      *(uint2*)(yS + c1) = w2;
    }
  }

#pragma unroll
  for (int j = 0; j < 4; ++j) { atomicAdd(&ls[c0 + j], s0[j]); atomicAdd(&lq[c0 + j], q0[j]); }
  if (tl) {
#pragma unroll
    for (int j = 0; j < 4; ++j) { atomicAdd(&ls[c1 + j], s1[j]); atomicAdd(&lq[c1 + j], q1[j]); }
  }
  __syncthreads();
  for (int i = tid; i < DP; i += 256) {
    atomicAdd(&bn_sum[i], ls[i]);
    atomicAdd(&bn_sq[i], lq[i]);
  }
}

// ---------------- MFMA Gram decode ----------------

__launch_bounds__(256)
__global__ void decode_kernel(const u16* __restrict__ H, float* __restrict__ out) {
  __shared__ __align__(16) u16 tile[4][2][NPG * BK];
  int tid = threadIdx.x, lane = tid & 63, wv = tid >> 6;
  int g = blockIdx.x * 4 + wv;
  const u16* Hg = H + (size_t)g * NPG * DP;
  const int ssl = lane & 3;
  int soff[4];
  const u16* sg[4];
#pragma unroll
  for (int i = 0; i < 4; ++i) {
    int r = (lane >> 2) + i * 16;
    soff[i] = r * BK + ((ssl ^ (r & 3) ^ ((r >> 2) & 3)) << 3);
    sg[i] = Hg + (size_t)r * DP + ssl * 8;
  }
  const int fr = lane & 15, fs = lane >> 4;
  const int fswz = ((fs ^ (fr & 3) ^ ((fr >> 2) & 3)) << 3);
  int foff[4];
#pragma unroll
  for (int i = 0; i < 4; ++i) foff[i] = (i * 16 + fr) * BK + fswz;

  u16* t0 = tile[wv][0];
  u16* t1 = tile[wv][1];
  uint4 rg[4];
#pragma unroll
  for (int i = 0; i < 4; ++i) rg[i] = *(const uint4*)(sg[i]);
#pragma unroll
  for (int i = 0; i < 4; ++i) *(uint4*)&t0[soff[i]] = rg[i];

  f32x4 acc[4][4];
#pragma unroll
  for (int i = 0; i < 4; ++i)
#pragma unroll
    for (int j = 0; j < 4; ++j) acc[i][j] = (f32x4){0.f, 0.f, 0.f, 0.f};

  for (int s = 0; s < DP / BK; ++s) {
    u16* cur = (s & 1) ? t1 : t0;
    u16* nxt = (s & 1) ? t0 : t1;
    const bool more = (s < DP / BK - 1);
    if (more) {
#pragma unroll
      for (int i = 0; i < 4; ++i) rg[i] = *(const uint4*)(sg[i] + (s + 1) * BK);
    }
    s16x8 af[4];
#pragma unroll
    for (int i = 0; i < 4; ++i) af[i] = *(const s16x8*)&cur[foff[i]];
#pragma unroll
    for (int i = 0; i < 4; ++i)
#pragma unroll
      for (int j = 0; j < 4; ++j)
        acc[i][j] = __builtin_amdgcn_mfma_f32_16x16x32_bf16(af[i], af[j], acc[i][j], 0, 0, 0);
    if (more) {
#pragma unroll
      for (int i = 0; i < 4; ++i) *(uint4*)&nxt[soff[i]] = rg[i];
    }
  }
  float* og = out + (size_t)g * NPG * NPG;
#pragma unroll
  for (int i = 0; i < 4; ++i) {
    int m0 = i * 16 + fs * 4;
#pragma unroll
    for (int j = 0; j < 4; ++j) {
      int n = j * 16 + fr;
#pragma unroll
      for (int r = 0; r < 4; ++r) og[(m0 + r) * NPG + n] = acc[i][j][r];
    }
  }
}

// ---------------- launch ----------------

extern "C" void kernel_launch(void* const* d_in, const int* in_sizes, int n_in,
                              void* d_out, int out_size, void* d_ws, size_t ws_size,
                              hipStream_t stream) {
  const int* xa = (const int*)d_in[0];
  const int* ei = (const int*)d_in[1];
  const float* emb = (const float*)d_in[2];
  const float* convW = (const float*)d_in[3];
  const float* convB = (const float*)d_in[4];
  const float* gamma = (const float*)d_in[5];
  const float* beta = (const float*)d_in[6];
  const float* postW = (const float*)d_in[7];
  const float* postB = (const float*)d_in[8];
  float* out = (float*)d_out;

  char* w = (char*)d_ws;
  u16* P = (u16*)w;          w += (size_t)(NN + 1) * DP * sizeof(u16);
  u16* Q = (u16*)w;          w += (size_t)(NN + 1) * DP * sizeof(u16);
  u16* Wp = (u16*)w;         w += (size_t)6 * 320 * DP * sizeof(u16);
  float* dinv = (float*)w;   w += (size_t)NN * sizeof(float);
  int* cnt = (int*)w;        w += (size_t)NN * sizeof(int);
  int* cnt_pad = (int*)w;    w += (size_t)NN * sizeof(int);
  int* indptr = (int*)w;     w += (size_t)(NN + 64) * sizeof(int);
  int* cursor = (int*)w;     w += (size_t)NN * sizeof(int);
  int* srcs = (int*)w;       w += (size_t)NEPAD * sizeof(int);
  int* partials = (int*)w;   w += 256 * sizeof(int);
  float* bnstats = (float*)w; w += (size_t)NLAY * 2 * DP * sizeof(float);

  size_t need = (size_t)(w - (char*)d_ws);
  if (ws_size < need) return;

  hipMemsetAsync(cnt, 0, (size_t)NN * sizeof(int), stream);
  hipMemsetAsync(bnstats, 0, (size_t)NLAY * 2 * DP * sizeof(float), stream);
  hist_kernel<<<NE / 256, 256, 0, stream>>>(ei, cnt);
  pad_dinv_kernel<<<NN / 256, 256, 0, stream>>>(cnt, cnt_pad, dinv);
  scan_block_kernel<<<NN / 1024, 1024, 0, stream>>>(cnt_pad, indptr, partials);
  scan_partials_kernel<<<1, 128, 0, stream>>>(partials);
  add_offsets_kernel<<<NN / 256, 256, 0, stream>>>(indptr, partials, cursor, cnt_pad);
  fill_csr_kernel<<<NE / 256, 256, 0, stream>>>(ei, cursor, srcs);
  pad_fill_kernel<<<NN / 256, 256, 0, stream>>>(cursor, indptr, srcs);
  wpad_kernel<<<(6 * 320 * DP + 255) / 256, 256, 0, stream>>>(convW, postW, Wp);
  embed_kernel<<<NN, 128, 0, stream>>>(xa, emb, P);
  zrow_kernel<<<1, 288, 0, stream>>>(P, Q);

  for (int l = 0; l < NLAY; ++l) {
    const float* bs = l ? bnstats + (size_t)(l - 1) * 2 * DP : nullptr;
    gemm_kernel<<<NN / 64, 256, 0, stream>>>(
        P, Wp + (size_t)l * 320 * DP, Q,
        bs, bs ? bs + DP : nullptr,
        l ? gamma + (size_t)(l - 1) * DIM : nullptr,
        l ? beta + (size_t)(l - 1) * DIM : nullptr,
        dinv, nullptr);
    spmm_kernel<<<NN / 64, 256, 0, stream>>>(Q, P, indptr, srcs, dinv,
                                             convB + (size_t)l * DIM,
                                             bnstats + (size_t)l * 2 * DP,
                                             bnstats + (size_t)l * 2 * DP + DP);
  }

  const float* bs5 = bnstats + (size_t)4 * 2 * DP;
  gemm_kernel<<<NN / 64, 256, 0, stream>>>(
      P, Wp + (size_t)5 * 320 * DP, Q, bs5, bs5 + DP,
      gamma + (size_t)4 * DIM, beta + (size_t)4 * DIM, nullptr, postB);

  decode_kernel<<<NGRAPH / 4, 256, 0, stream>>>(Q, out);
}